// Round 1
// baseline (1072.672 us; speedup 1.0000x reference)
//
#include <hip/hip_runtime.h>
#include <hip/hip_bf16.h>

#define BATCH   32768
#define DM      1024
#define NE      16
#define THRESHF 0.3f

// ws layout (bytes)
#define CTRL_OFF 131072                 // after idx[BATCH] (int32)
#define PERM_OFF 132096                 // perm int32[34816]
#define XG_OFF   272384                 // Xg bf16[34816*1024]
#define WB_OFF   71575552ull            // Wb bf16[16*1024*1024]
#define WS_NEED  (WB_OFF + (size_t)NE * DM * DM * 2)
#define WS_MIN   (PERM_OFF + 34816 * 4)

typedef __attribute__((ext_vector_type(8))) short bf16x8;
typedef __attribute__((ext_vector_type(4))) float f32x4;

static __device__ __forceinline__ unsigned short f2bf(float f) {
    union { float f; unsigned u; } v; v.f = f;
    unsigned r = (v.u + 0x7FFFu + ((v.u >> 16) & 1u)) >> 16;  // RNE
    return (unsigned short)r;
}

static __device__ __forceinline__ void gload_lds16(const void* g, void* s) {
    __builtin_amdgcn_global_load_lds(
        (const __attribute__((address_space(1))) void*)g,
        (__attribute__((address_space(3))) void*)s, 16, 0, 0);
}

__global__ void k_init(unsigned* counts) {
    if (threadIdx.x < 32) counts[threadIdx.x] = 0;  // counts[16] + cursor[16]
}

// Router: f64 scores vs ternary signatures, argmax (first-wins), histogram.
__global__ __launch_bounds__(256) void k_router(const float* __restrict__ x,
                                                const float* __restrict__ sig,
                                                int* __restrict__ idx,
                                                unsigned* __restrict__ counts,
                                                float* __restrict__ outIdx) {
    const int t = threadIdx.x, w = t >> 6, l = t & 63;
    // per-lane ternary pack: pack[k] holds 16 experts x 2 bits for position
    // pos(k=j*4+c) = (j*64+l)*4 + c   (row-independent)
    unsigned pack[16];
#pragma unroll
    for (int j = 0; j < 4; ++j)
#pragma unroll
        for (int c = 0; c < 4; ++c) {
            const int pos = (j * 64 + l) * 4 + c;
            unsigned wv = 0;
#pragma unroll
            for (int e = 0; e < NE; ++e) {
                float s = sig[e * DM + pos];
                unsigned q2 = (s > THRESHF) ? 1u : ((s < -THRESHF) ? 2u : 0u);
                wv |= q2 << (2 * e);
            }
            pack[j * 4 + c] = wv;
        }

    const int waveg = blockIdx.x * 4 + w;  // 4096 waves, 8 rows each
    for (int r = 0; r < 8; ++r) {
        const int row = waveg * 8 + r;
        double xd[16];
#pragma unroll
        for (int j = 0; j < 4; ++j) {
            float4 v = *(const float4*)&x[(size_t)row * DM + (j * 64 + l) * 4];
            xd[j * 4 + 0] = v.x; xd[j * 4 + 1] = v.y;
            xd[j * 4 + 2] = v.z; xd[j * 4 + 3] = v.w;
        }
        double acc[NE];
#pragma unroll
        for (int e = 0; e < NE; ++e) acc[e] = 0.0;
#pragma unroll
        for (int k = 0; k < 16; ++k) {
            const unsigned wv = pack[k];
            const double xv = xd[k];
#pragma unroll
            for (int e = 0; e < NE; ++e) {
                unsigned q2 = (wv >> (2 * e)) & 3u;
                acc[e] += (q2 == 1u) ? xv : ((q2 == 2u) ? -xv : 0.0);
            }
        }
#pragma unroll
        for (int e = 0; e < NE; ++e) {
            double s = acc[e];
            for (int m = 32; m >= 1; m >>= 1) s += __shfl_xor(s, m, 64);
            acc[e] = s;
        }
        if (l == 0) {
            double best = acc[0]; int bi = 0;
#pragma unroll
            for (int e = 1; e < NE; ++e)
                if (acc[e] > best) { best = acc[e]; bi = e; }
            idx[row] = bi;
            outIdx[row] = (float)bi;
            atomicAdd(&counts[bi], 1u);
        }
    }
}

// Tile-granular prefix: tileBase[e] = #128-row tiles before expert e.
__global__ void k_scan(const unsigned* counts, int* tileBase) {
    if (threadIdx.x == 0) {
        int acc = 0;
        for (int e = 0; e < NE; ++e) {
            tileBase[e] = acc;
            acc += (int)((counts[e] + 127u) / 128u);
        }
        tileBase[NE] = acc;
    }
}

// Scatter rows into padded packed order; optionally gather x -> bf16 Xg.
__global__ __launch_bounds__(256) void k_scatter(const float* __restrict__ x,
                                                 const int* __restrict__ idx,
                                                 unsigned* __restrict__ cursor,
                                                 const int* __restrict__ tileBase,
                                                 int* __restrict__ perm,
                                                 unsigned short* __restrict__ Xg,
                                                 int copyX) {
    const int t = threadIdx.x, w = t >> 6, l = t & 63;
    const int row = blockIdx.x * 4 + w;
    int p = 0;
    if (l == 0) {
        const int e = idx[row];
        const unsigned rank = atomicAdd(&cursor[e], 1u);
        p = tileBase[e] * 128 + (int)rank;
        perm[p] = row;
    }
    p = __shfl(p, 0, 64);
    if (copyX) {
#pragma unroll
        for (int j = 0; j < 4; ++j) {
            float4 v = *(const float4*)&x[(size_t)row * DM + (j * 64 + l) * 4];
            ushort4 o = make_ushort4(f2bf(v.x), f2bf(v.y), f2bf(v.z), f2bf(v.w));
            *(ushort4*)&Xg[(size_t)p * DM + (j * 64 + l) * 4] = o;
        }
    }
}

// Zero pad rows of each expert segment (so MFMA A-tiles are safe).
__global__ void k_zeropad(const unsigned* counts, const int* tileBase,
                          unsigned short* __restrict__ Xg) {
    const int e = blockIdx.x;
    const int start = tileBase[e] * 128 + (int)counts[e];
    const int end = tileBase[e + 1] * 128;
    const int n16 = (end - start) * (DM / 8);
    int4 z = make_int4(0, 0, 0, 0);
    for (int c = threadIdx.x; c < n16; c += blockDim.x)
        *(int4*)&Xg[(size_t)start * DM + (size_t)c * 8] = z;
}

// W f32 -> bf16 (one shot; 16M elems, 8 per thread).
__global__ __launch_bounds__(256) void k_convw(const float* __restrict__ W,
                                               unsigned short* __restrict__ Wb) {
    const size_t g = ((size_t)blockIdx.x * 256 + threadIdx.x) * 8;
    float4 a = *(const float4*)&W[g];
    float4 b = *(const float4*)&W[g + 4];
    *(ushort4*)&Wb[g]     = make_ushort4(f2bf(a.x), f2bf(a.y), f2bf(a.z), f2bf(a.w));
    *(ushort4*)&Wb[g + 4] = make_ushort4(f2bf(b.x), f2bf(b.y), f2bf(b.z), f2bf(b.w));
}

// Grouped bf16 GEMM: 128x128 tile, BK=32, 4 waves (2x2), 16x16x32 MFMA.
// MODE 0: A/B staged via global_load_lds from pre-converted bf16 buffers.
// MODE 1 (small ws): reg-staged f32->bf16 conversion from x (via perm) and W.
// Epilogue: +bias, ReLU, +x residual, scatter-store to out rows.
template <int MODE>
__global__ __launch_bounds__(256) void k_gemm(const unsigned short* __restrict__ Xg,
                                              const unsigned short* __restrict__ Wb,
                                              const float* __restrict__ x,
                                              const float* __restrict__ W,
                                              const float* __restrict__ bias,
                                              const int* __restrict__ perm,
                                              const int* __restrict__ tileBase,
                                              const unsigned* __restrict__ counts,
                                              float* __restrict__ out) {
    __shared__ unsigned short A_lds[128 * 32];
    __shared__ unsigned short B_lds[128 * 32];

    const int bx = blockIdx.x;
    const int total = tileBase[NE];
    if (bx >= total) return;
    int e = 0;
    while (e < NE - 1 && tileBase[e + 1] <= bx) ++e;
    const int ltile = bx - tileBase[e];
    const int valid = (int)counts[e] - ltile * 128;  // 1..128 valid rows
    const int n0 = blockIdx.y * 128;

    const int t = threadIdx.x, w = t >> 6, l = t & 63;
    const int wr = w >> 1, wc = w & 1;
    const int lc = l & 15, lr = l >> 4;

    f32x4 acc[4][4];
#pragma unroll
    for (int m = 0; m < 4; ++m)
#pragma unroll
        for (int n = 0; n < 4; ++n) acc[m][n] = (f32x4){0.f, 0.f, 0.f, 0.f};

    const size_t aRowBase = (size_t)bx * 128;
    const unsigned short* Ag = Xg + aRowBase * DM;
    const unsigned short* Bg = Wb + ((size_t)e * DM + n0) * DM;

    for (int kt = 0; kt < DM / 32; ++kt) {
        __syncthreads();
        if (MODE == 0) {
#pragma unroll
            for (int rd = 0; rd < 2; ++rd) {
                const int c = rd * 256 + t;  // c>>2 = row, c&3 = 8-elem chunk
                gload_lds16(Ag + (size_t)(c >> 2) * DM + kt * 32 + (c & 3) * 8,
                            &A_lds[(size_t)(rd * 256 + w * 64) * 8]);
                gload_lds16(Bg + (size_t)(c >> 2) * DM + kt * 32 + (c & 3) * 8,
                            &B_lds[(size_t)(rd * 256 + w * 64) * 8]);
            }
        } else {
#pragma unroll
            for (int rd = 0; rd < 2; ++rd) {
                const int c = rd * 256 + t;
                const int r = c >> 2, h = c & 3;
                const float* wp = W + ((size_t)e * DM + n0 + r) * DM + kt * 32 + h * 8;
                float4 b0 = *(const float4*)wp;
                float4 b1 = *(const float4*)(wp + 4);
                *(ushort4*)&B_lds[c * 8]     = make_ushort4(f2bf(b0.x), f2bf(b0.y), f2bf(b0.z), f2bf(b0.w));
                *(ushort4*)&B_lds[c * 8 + 4] = make_ushort4(f2bf(b1.x), f2bf(b1.y), f2bf(b1.z), f2bf(b1.w));
                ushort4 p0 = make_ushort4(0, 0, 0, 0), p1 = p0;
                if (r < valid) {
                    const int orow = perm[aRowBase + r];
                    const float* xp = x + (size_t)orow * DM + kt * 32 + h * 8;
                    float4 a0 = *(const float4*)xp;
                    float4 a1 = *(const float4*)(xp + 4);
                    p0 = make_ushort4(f2bf(a0.x), f2bf(a0.y), f2bf(a0.z), f2bf(a0.w));
                    p1 = make_ushort4(f2bf(a1.x), f2bf(a1.y), f2bf(a1.z), f2bf(a1.w));
                }
                *(ushort4*)&A_lds[c * 8]     = p0;
                *(ushort4*)&A_lds[c * 8 + 4] = p1;
            }
        }
        __syncthreads();

        bf16x8 af[4], bf[4];
#pragma unroll
        for (int m = 0; m < 4; ++m)
            af[m] = *(const bf16x8*)&A_lds[(wr * 64 + m * 16 + lc) * 32 + lr * 8];
#pragma unroll
        for (int n = 0; n < 4; ++n)
            bf[n] = *(const bf16x8*)&B_lds[(wc * 64 + n * 16 + lc) * 32 + lr * 8];
#pragma unroll
        for (int m = 0; m < 4; ++m)
#pragma unroll
            for (int n = 0; n < 4; ++n)
                acc[m][n] = __builtin_amdgcn_mfma_f32_16x16x32_bf16(af[m], bf[n], acc[m][n], 0, 0, 0);
    }

    float bv[4];
#pragma unroll
    for (int n = 0; n < 4; ++n) bv[n] = bias[e * DM + n0 + wc * 64 + n * 16 + lc];

#pragma unroll
    for (int m = 0; m < 4; ++m) {
#pragma unroll
        for (int reg = 0; reg < 4; ++reg) {
            const int rit = wr * 64 + m * 16 + lr * 4 + reg;  // row in tile
            if (rit < valid) {
                const int orow = perm[aRowBase + rit];
                const float* xr = x + (size_t)orow * DM;
                float* op = out + (size_t)orow * DM;
#pragma unroll
                for (int n = 0; n < 4; ++n) {
                    const int col = n0 + wc * 64 + n * 16 + lc;
                    float v = acc[m][n][reg] + bv[n];
                    v = v > 0.f ? v : 0.f;
                    op[col] = v + xr[col];
                }
            }
        }
    }
}

extern "C" void kernel_launch(void* const* d_in, const int* in_sizes, int n_in,
                              void* d_out, int out_size, void* d_ws, size_t ws_size,
                              hipStream_t stream) {
    const float* x    = (const float*)d_in[0];
    const float* sig  = (const float*)d_in[1];
    const float* W    = (const float*)d_in[2];
    const float* bias = (const float*)d_in[3];
    float* out = (float*)d_out;
    float* outIdx = out + (size_t)BATCH * DM;

    char* ws = (char*)d_ws;
    int* idx = (int*)ws;
    unsigned* counts = (unsigned*)(ws + CTRL_OFF);
    unsigned* cursor = counts + 16;
    int* tileBase = (int*)(counts + 32);
    int* perm = (int*)(ws + PERM_OFF);
    unsigned short* Xg = (unsigned short*)(ws + XG_OFF);
    unsigned short* Wb = (unsigned short*)(ws + WB_OFF);

    const bool full = ws_size >= WS_NEED;

    k_init<<<1, 64, 0, stream>>>(counts);
    k_router<<<1024, 256, 0, stream>>>(x, sig, idx, counts, outIdx);
    k_scan<<<1, 64, 0, stream>>>(counts, tileBase);
    k_scatter<<<8192, 256, 0, stream>>>(x, idx, cursor, tileBase, perm, Xg, full ? 1 : 0);
    if (full) {
        k_zeropad<<<16, 256, 0, stream>>>(counts, tileBase, Xg);
        k_convw<<<8192, 256, 0, stream>>>(W, Wb);
        k_gemm<0><<<dim3(271, 8), 256, 0, stream>>>(Xg, Wb, x, W, bias, perm, tileBase, counts, out);
    } else {
        k_gemm<1><<<dim3(271, 8), 256, 0, stream>>>(Xg, Wb, x, W, bias, perm, tileBase, counts, out);
    }
}

// Round 2
// 412.497 us; speedup vs baseline: 2.6004x; 2.6004x over previous
//
#include <hip/hip_runtime.h>
#include <hip/hip_bf16.h>

#define BATCH   32768
#define DM      1024
#define NE      16
#define THRESHF 0.3f

// ws layout (bytes)
// idx   @ 0          : int32[32768]                 = 131072
// ctrl  @ 131072     : u32[2048] (8192 B)
//    [e*16]        counts (strided, one 64B line per expert)
//    [256 + e*16]  cursor (strided)
//    [512..528]    tileBase int[17]
//    [1024..2047]  packT u32[1024]  (pm | mm<<16 per dim)
// perm  @ 139264     : int32[34816]                 = 139264
// Xg    @ 278528     : bf16[34816*1024]             = 71303168
// Wb    @ 71581696   : bf16[16*1024*1024]           = 33554432
#define CTRL_OFF 131072
#define PERM_OFF 139264
#define XG_OFF   278528
#define WB_OFF   71581696ull
#define WS_NEED  (WB_OFF + (size_t)NE * DM * DM * 2)

typedef __attribute__((ext_vector_type(8))) short bf16x8;
typedef __attribute__((ext_vector_type(4))) float f32x4;

static __device__ __forceinline__ unsigned short f2bf(float f) {
    union { float f; unsigned u; } v; v.f = f;
    unsigned r = (v.u + 0x7FFFu + ((v.u >> 16) & 1u)) >> 16;  // RNE
    return (unsigned short)r;
}

static __device__ __forceinline__ void gload_lds16(const void* g, void* s) {
    __builtin_amdgcn_global_load_lds(
        (const __attribute__((address_space(1))) void*)g,
        (__attribute__((address_space(3))) void*)s, 16, 0, 0);
}

// Zero counts/cursor/tileBase and build ternary pack table.
// grid 4x256 -> t = 0..1023 (one dim each).
__global__ void k_init(const float* __restrict__ sig, unsigned* __restrict__ ctrl) {
    const int t = blockIdx.x * 256 + threadIdx.x;
    if (t < 544) ctrl[t] = 0;
    unsigned pm = 0, mm = 0;
#pragma unroll
    for (int e = 0; e < NE; ++e) {
        float s = sig[e * DM + t];
        pm |= (s > THRESHF ? 1u : 0u) << e;
        mm |= (s < -THRESHF ? 1u : 0u) << e;
    }
    ctrl[1024 + t] = pm | (mm << 16);
}

// Router: exact f64 ternary scores, LDS transpose-reduce, distributed argmax.
// 2048 blocks x 4 waves, 4 rows per wave.
__global__ __launch_bounds__(256, 4) void k_router(const float* __restrict__ x,
                                                   unsigned* __restrict__ ctrl,
                                                   int* __restrict__ idx,
                                                   float* __restrict__ outIdx) {
    __shared__ double S[4][64][17];
    const int t = threadIdx.x, w = t >> 6, l = t & 63;
    const unsigned* packT = ctrl + 1024;

    unsigned pk[16];
#pragma unroll
    for (int k = 0; k < 16; ++k)
        pk[k] = packT[((k >> 2) * 64 + l) * 4 + (k & 3)];

    const int wid = blockIdx.x * 4 + w;  // 0..8191, 4 rows each

    float4 nxt[4];
    {
        const float* xr = x + (size_t)(wid * 4) * DM;
#pragma unroll
        for (int j = 0; j < 4; ++j) nxt[j] = *(const float4*)&xr[(j * 64 + l) * 4];
    }

    for (int r = 0; r < 4; ++r) {
        float4 cur[4];
#pragma unroll
        for (int j = 0; j < 4; ++j) cur[j] = nxt[j];
        if (r < 3) {
            const float* xn = x + (size_t)(wid * 4 + r + 1) * DM;
#pragma unroll
            for (int j = 0; j < 4; ++j) nxt[j] = *(const float4*)&xn[(j * 64 + l) * 4];
        }

        double xd[16];
#pragma unroll
        for (int j = 0; j < 4; ++j) {
            xd[j * 4 + 0] = cur[j].x; xd[j * 4 + 1] = cur[j].y;
            xd[j * 4 + 2] = cur[j].z; xd[j * 4 + 3] = cur[j].w;
        }

        // two expert-groups of 8 to halve accumulator register pressure
#pragma unroll
        for (int g = 0; g < 2; ++g) {
            double acc[8];
#pragma unroll
            for (int e = 0; e < 8; ++e) acc[e] = 0.0;
#pragma unroll
            for (int k = 0; k < 16; ++k) {
                const double xv = xd[k];
                const unsigned pb = pk[k] >> (g * 8);
                const unsigned mb = pk[k] >> (16 + g * 8);
#pragma unroll
                for (int e = 0; e < 8; ++e)
                    acc[e] += ((pb >> e) & 1u) ? xv : (((mb >> e) & 1u) ? -xv : 0.0);
            }
#pragma unroll
            for (int e = 0; e < 8; ++e) S[w][l][g * 8 + e] = acc[e];
        }
        asm volatile("s_waitcnt lgkmcnt(0)" ::: "memory");
        __builtin_amdgcn_sched_barrier(0);

        // lane (e = l&15, q = l>>4) sums 16 lanes' partials for expert e
        const int e = l & 15, q = l >> 4;
        double p = 0.0;
#pragma unroll
        for (int i = 0; i < 16; ++i) p += S[w][q * 16 + i][e];
        p += __shfl_xor(p, 16, 64);
        p += __shfl_xor(p, 32, 64);

        // first-wins argmax across the 16-lane expert dimension
        double bv = p; int bi = e;
#pragma unroll
        for (int m = 1; m < 16; m <<= 1) {
            double ov = __shfl_xor(bv, m, 64);
            int oi = __shfl_xor(bi, m, 64);
            bool take = (ov > bv) || (ov == bv && oi < bi);
            bv = take ? ov : bv;
            bi = take ? oi : bi;
        }

        const int row = wid * 4 + r;
        if (l == 0) {
            idx[row] = bi;
            outIdx[row] = (float)bi;
            atomicAdd(&ctrl[bi * 16], 1u);  // strided: one cacheline per counter
        }
    }
}

// Tile-granular prefix: tileBase[e] = #128-row tiles before expert e.
__global__ void k_scan(unsigned* __restrict__ ctrl) {
    if (threadIdx.x == 0) {
        int* tileBase = (int*)(ctrl + 512);
        int acc = 0;
        for (int e = 0; e < NE; ++e) {
            tileBase[e] = acc;
            acc += (int)((ctrl[e * 16] + 127u) / 128u);
        }
        tileBase[NE] = acc;
    }
}

// Scatter rows into padded packed order; gather x -> bf16 Xg.
__global__ __launch_bounds__(256) void k_scatter(const float* __restrict__ x,
                                                 const int* __restrict__ idx,
                                                 unsigned* __restrict__ ctrl,
                                                 int* __restrict__ perm,
                                                 unsigned short* __restrict__ Xg,
                                                 int copyX) {
    const int t = threadIdx.x, w = t >> 6, l = t & 63;
    const int row = blockIdx.x * 4 + w;
    const int* tileBase = (const int*)(ctrl + 512);
    int p = 0;
    if (l == 0) {
        const int e = idx[row];
        const unsigned rank = atomicAdd(&ctrl[256 + e * 16], 1u);
        p = tileBase[e] * 128 + (int)rank;
        perm[p] = row;
    }
    p = __shfl(p, 0, 64);
    if (copyX) {
#pragma unroll
        for (int j = 0; j < 4; ++j) {
            float4 v = *(const float4*)&x[(size_t)row * DM + (j * 64 + l) * 4];
            ushort4 o = make_ushort4(f2bf(v.x), f2bf(v.y), f2bf(v.z), f2bf(v.w));
            *(ushort4*)&Xg[(size_t)p * DM + (j * 64 + l) * 4] = o;
        }
    }
}

// Zero pad rows of each expert segment (so MFMA A-tiles are safe).
__global__ void k_zeropad(const unsigned* __restrict__ ctrl,
                          unsigned short* __restrict__ Xg) {
    const int e = blockIdx.x;
    const int* tileBase = (const int*)(ctrl + 512);
    const int start = tileBase[e] * 128 + (int)ctrl[e * 16];
    const int end = tileBase[e + 1] * 128;
    const int n16 = (end - start) * (DM / 8);
    int4 z = make_int4(0, 0, 0, 0);
    for (int c = threadIdx.x; c < n16; c += blockDim.x)
        *(int4*)&Xg[(size_t)start * DM + (size_t)c * 8] = z;
}

// W f32 -> bf16 (16M elems, 8 per thread).
__global__ __launch_bounds__(256) void k_convw(const float* __restrict__ W,
                                               unsigned short* __restrict__ Wb) {
    const size_t g = ((size_t)blockIdx.x * 256 + threadIdx.x) * 8;
    float4 a = *(const float4*)&W[g];
    float4 b = *(const float4*)&W[g + 4];
    *(ushort4*)&Wb[g]     = make_ushort4(f2bf(a.x), f2bf(a.y), f2bf(a.z), f2bf(a.w));
    *(ushort4*)&Wb[g + 4] = make_ushort4(f2bf(b.x), f2bf(b.y), f2bf(b.z), f2bf(b.w));
}

// Grouped bf16 GEMM: 128x128 tile, BK=32, 4 waves (2x2), 16x16x32 MFMA.
// MODE 0: A/B staged via global_load_lds from pre-converted bf16 buffers.
// MODE 1 (small ws): reg-staged f32->bf16 conversion from x (via perm) and W.
// Epilogue: +bias, ReLU, +x residual, scatter-store to out rows.
template <int MODE>
__global__ __launch_bounds__(256) void k_gemm(const unsigned short* __restrict__ Xg,
                                              const unsigned short* __restrict__ Wb,
                                              const float* __restrict__ x,
                                              const float* __restrict__ W,
                                              const float* __restrict__ bias,
                                              const int* __restrict__ perm,
                                              const unsigned* __restrict__ ctrl,
                                              float* __restrict__ out) {
    __shared__ unsigned short A_lds[128 * 32];
    __shared__ unsigned short B_lds[128 * 32];

    const int* tileBase = (const int*)(ctrl + 512);

    // bijective XCD-aware swizzle over NWGX=271 (m204): q=33, r=7
    int bx;
    {
        const int orig = blockIdx.x;
        const int xcd = orig & 7, loc = orig >> 3;
        bx = (xcd < 7 ? xcd * 34 : 238 + (xcd - 7) * 33) + loc;
    }
    const int total = tileBase[NE];
    if (bx >= total) return;
    int e = 0;
    while (e < NE - 1 && tileBase[e + 1] <= bx) ++e;
    const int ltile = bx - tileBase[e];
    const int valid = (int)ctrl[e * 16] - ltile * 128;  // 1..128 valid rows
    const int n0 = blockIdx.y * 128;

    const int t = threadIdx.x, w = t >> 6, l = t & 63;
    const int wr = w >> 1, wc = w & 1;
    const int lc = l & 15, lr = l >> 4;

    f32x4 acc[4][4];
#pragma unroll
    for (int m = 0; m < 4; ++m)
#pragma unroll
        for (int n = 0; n < 4; ++n) acc[m][n] = (f32x4){0.f, 0.f, 0.f, 0.f};

    const size_t aRowBase = (size_t)bx * 128;
    const unsigned short* Ag = Xg + aRowBase * DM;
    const unsigned short* Bg = Wb + ((size_t)e * DM + n0) * DM;

    for (int kt = 0; kt < DM / 32; ++kt) {
        __syncthreads();
        if (MODE == 0) {
#pragma unroll
            for (int rd = 0; rd < 2; ++rd) {
                const int c = rd * 256 + t;  // c>>2 = row, c&3 = 8-elem chunk
                gload_lds16(Ag + (size_t)(c >> 2) * DM + kt * 32 + (c & 3) * 8,
                            &A_lds[(size_t)(rd * 256 + w * 64) * 8]);
                gload_lds16(Bg + (size_t)(c >> 2) * DM + kt * 32 + (c & 3) * 8,
                            &B_lds[(size_t)(rd * 256 + w * 64) * 8]);
            }
        } else {
#pragma unroll
            for (int rd = 0; rd < 2; ++rd) {
                const int c = rd * 256 + t;
                const int r = c >> 2, h = c & 3;
                const float* wp = W + ((size_t)e * DM + n0 + r) * DM + kt * 32 + h * 8;
                float4 b0 = *(const float4*)wp;
                float4 b1 = *(const float4*)(wp + 4);
                *(ushort4*)&B_lds[c * 8]     = make_ushort4(f2bf(b0.x), f2bf(b0.y), f2bf(b0.z), f2bf(b0.w));
                *(ushort4*)&B_lds[c * 8 + 4] = make_ushort4(f2bf(b1.x), f2bf(b1.y), f2bf(b1.z), f2bf(b1.w));
                ushort4 p0 = make_ushort4(0, 0, 0, 0), p1 = p0;
                if (r < valid) {
                    const int orow = perm[aRowBase + r];
                    const float* xp = x + (size_t)orow * DM + kt * 32 + h * 8;
                    float4 a0 = *(const float4*)xp;
                    float4 a1 = *(const float4*)(xp + 4);
                    p0 = make_ushort4(f2bf(a0.x), f2bf(a0.y), f2bf(a0.z), f2bf(a0.w));
                    p1 = make_ushort4(f2bf(a1.x), f2bf(a1.y), f2bf(a1.z), f2bf(a1.w));
                }
                *(ushort4*)&A_lds[c * 8]     = p0;
                *(ushort4*)&A_lds[c * 8 + 4] = p1;
            }
        }
        __syncthreads();

        bf16x8 af[4], bf[4];
#pragma unroll
        for (int m = 0; m < 4; ++m)
            af[m] = *(const bf16x8*)&A_lds[(wr * 64 + m * 16 + lc) * 32 + lr * 8];
#pragma unroll
        for (int n = 0; n < 4; ++n)
            bf[n] = *(const bf16x8*)&B_lds[(wc * 64 + n * 16 + lc) * 32 + lr * 8];
#pragma unroll
        for (int m = 0; m < 4; ++m)
#pragma unroll
            for (int n = 0; n < 4; ++n)
                acc[m][n] = __builtin_amdgcn_mfma_f32_16x16x32_bf16(af[m], bf[n], acc[m][n], 0, 0, 0);
    }

    float bv[4];
#pragma unroll
    for (int n = 0; n < 4; ++n) bv[n] = bias[e * DM + n0 + wc * 64 + n * 16 + lc];

#pragma unroll
    for (int m = 0; m < 4; ++m) {
#pragma unroll
        for (int reg = 0; reg < 4; ++reg) {
            const int rit = wr * 64 + m * 16 + lr * 4 + reg;  // row in tile
            if (rit < valid) {
                const int orow = perm[aRowBase + rit];
                const float* xr = x + (size_t)orow * DM;
                float* op = out + (size_t)orow * DM;
#pragma unroll
                for (int n = 0; n < 4; ++n) {
                    const int col = n0 + wc * 64 + n * 16 + lc;
                    float v = acc[m][n][reg] + bv[n];
                    v = v > 0.f ? v : 0.f;
                    op[col] = v + xr[col];
                }
            }
        }
    }
}

extern "C" void kernel_launch(void* const* d_in, const int* in_sizes, int n_in,
                              void* d_out, int out_size, void* d_ws, size_t ws_size,
                              hipStream_t stream) {
    const float* x    = (const float*)d_in[0];
    const float* sig  = (const float*)d_in[1];
    const float* W    = (const float*)d_in[2];
    const float* bias = (const float*)d_in[3];
    float* out = (float*)d_out;
    float* outIdx = out + (size_t)BATCH * DM;

    char* ws = (char*)d_ws;
    int* idx = (int*)ws;
    unsigned* ctrl = (unsigned*)(ws + CTRL_OFF);
    int* perm = (int*)(ws + PERM_OFF);
    unsigned short* Xg = (unsigned short*)(ws + XG_OFF);
    unsigned short* Wb = (unsigned short*)(ws + WB_OFF);

    const bool full = ws_size >= WS_NEED;

    k_init<<<4, 256, 0, stream>>>(sig, ctrl);
    k_router<<<2048, 256, 0, stream>>>(x, ctrl, idx, outIdx);
    k_scan<<<1, 64, 0, stream>>>(ctrl);
    k_scatter<<<8192, 256, 0, stream>>>(x, idx, ctrl, perm, Xg, full ? 1 : 0);
    if (full) {
        k_zeropad<<<16, 256, 0, stream>>>(ctrl, Xg);
        k_convw<<<8192, 256, 0, stream>>>(W, Wb);
        k_gemm<0><<<dim3(271, 8), 256, 0, stream>>>(Xg, Wb, x, W, bias, perm, ctrl, out);
    } else {
        k_gemm<1><<<dim3(271, 8), 256, 0, stream>>>(Xg, Wb, x, W, bias, perm, ctrl, out);
    }
}

// Round 3
// 373.666 us; speedup vs baseline: 2.8707x; 1.1039x over previous
//
#include <hip/hip_runtime.h>
#include <hip/hip_bf16.h>

#define BATCH   32768
#define DM      1024
#define NE      16
#define THRESHF 0.3f
#define MARGIN  0.02f

// ws layout (bytes)
// idx   @ 0          : int32[32768]            = 131072
// ctrl  @ 131072     : u32[2048] (8192 B)
//    [e*16]        counts (one 64B line per expert)
//    [256 + e*16]  cursor (strided)
//    [512..528]    tileBase int[17]
//    [1024..2047]  packT u32[1024] (pm | mm<<16 per dim)
// perm  @ 139264     : int32[34816]            (prefilled 0 for pad slots)
// Xbf   @ 278528     : bf16[32768*1024]        = 67108864
// Wb    @ 67387392   : bf16[16*1024*1024]      = 33554432   (ends ~96.3 MB)
#define CTRL_OFF 131072
#define PERM_OFF 139264
#define XBF_OFF  278528
#define WB_OFF   67387392ull
#define WS_NEED  (WB_OFF + (size_t)NE * DM * DM * 2)

typedef __attribute__((ext_vector_type(8))) short bf16x8;
typedef __attribute__((ext_vector_type(4))) float f32x4;

static __device__ __forceinline__ unsigned short f2bf(float f) {
    union { float f; unsigned u; } v; v.f = f;
    unsigned r = (v.u + 0x7FFFu + ((v.u >> 16) & 1u)) >> 16;  // RNE
    return (unsigned short)r;
}

static __device__ __forceinline__ void gload_lds16(const void* g, void* s) {
    __builtin_amdgcn_global_load_lds(
        (const __attribute__((address_space(1))) void*)g,
        (__attribute__((address_space(3))) void*)s, 16, 0, 0);
}

// Zero ctrl, build ternary pack table, prefill perm with 0.
__global__ void k_init(const float* __restrict__ sig, unsigned* __restrict__ ctrl,
                       int* __restrict__ perm) {
    const int t = blockIdx.x * 256 + threadIdx.x;  // 0..10239
    if (t < 544) ctrl[t] = 0;
    if (t < 1024) {
        unsigned pm = 0, mm = 0;
#pragma unroll
        for (int e = 0; e < NE; ++e) {
            float s = sig[e * DM + t];
            pm |= (s > THRESHF ? 1u : 0u) << e;
            mm |= (s < -THRESHF ? 1u : 0u) << e;
        }
        ctrl[1024 + t] = pm | (mm << 16);
    }
    if (t < 8704) ((int4*)perm)[t] = make_int4(0, 0, 0, 0);
}

// Router: f32 ternary scores + top-2 margin; exact f64 fallback for close
// calls; writes bf16 copy of x (Xbf) from registers.
__global__ __launch_bounds__(256) void k_router(const float* __restrict__ x,
                                                unsigned* __restrict__ ctrl,
                                                int* __restrict__ idx,
                                                float* __restrict__ outIdx,
                                                unsigned short* __restrict__ Xbf,
                                                int writeXbf) {
    __shared__ float S[4][64][17];
    const int t = threadIdx.x, w = t >> 6, l = t & 63;
    const unsigned* packT = ctrl + 1024;

    unsigned pk[16];
#pragma unroll
    for (int k = 0; k < 16; ++k)
        pk[k] = packT[((k >> 2) * 64 + l) * 4 + (k & 3)];

    const int wid = blockIdx.x * 4 + w;  // 0..8191, 4 rows each

    float4 nxt[4];
    {
        const float* xr = x + (size_t)(wid * 4) * DM;
#pragma unroll
        for (int j = 0; j < 4; ++j) nxt[j] = *(const float4*)&xr[(j * 64 + l) * 4];
    }

    for (int r = 0; r < 4; ++r) {
        float4 cur[4];
#pragma unroll
        for (int j = 0; j < 4; ++j) cur[j] = nxt[j];
        if (r < 3) {
            const float* xn = x + (size_t)(wid * 4 + r + 1) * DM;
#pragma unroll
            for (int j = 0; j < 4; ++j) nxt[j] = *(const float4*)&xn[(j * 64 + l) * 4];
        }
        const int row = wid * 4 + r;

        if (writeXbf) {
            unsigned short* xb = Xbf + (size_t)row * DM;
#pragma unroll
            for (int j = 0; j < 4; ++j)
                *(ushort4*)&xb[(j * 64 + l) * 4] =
                    make_ushort4(f2bf(cur[j].x), f2bf(cur[j].y), f2bf(cur[j].z), f2bf(cur[j].w));
        }

        float xs[16];
#pragma unroll
        for (int j = 0; j < 4; ++j) {
            xs[j * 4 + 0] = cur[j].x; xs[j * 4 + 1] = cur[j].y;
            xs[j * 4 + 2] = cur[j].z; xs[j * 4 + 3] = cur[j].w;
        }

        float acc[16];
#pragma unroll
        for (int e = 0; e < 16; ++e) acc[e] = 0.f;
#pragma unroll
        for (int k = 0; k < 16; ++k) {
            const int xi = __float_as_int(xs[k]);
            const int xni = xi ^ 0x80000000;
            const unsigned w32 = pk[k];
#pragma unroll
            for (int e = 0; e < 16; ++e) {
                const int pmask = (int)(w32 << (31 - e)) >> 31;        // bit e
                const int mmask = (int)(w32 << (15 - e)) >> 31;        // bit 16+e
                acc[e] += __int_as_float((pmask & xi) | (mmask & xni));
            }
        }
#pragma unroll
        for (int e = 0; e < 16; ++e) S[w][l][e] = acc[e];
        asm volatile("s_waitcnt lgkmcnt(0)" ::: "memory");
        __builtin_amdgcn_sched_barrier(0);

        // lane (e = l&15, q = l>>4) sums 16 lanes' partials for expert e
        const int e = l & 15, q = l >> 4;
        float p = 0.f;
#pragma unroll
        for (int i = 0; i < 16; ++i) p += S[w][q * 16 + i][e];
        p += __shfl_xor(p, 16, 64);
        p += __shfl_xor(p, 32, 64);

        // first-wins argmax + second-best value across 16-lane expert dim
        float bv = p; int bi = e; float sv = -3.4e38f;
#pragma unroll
        for (int m = 1; m < 16; m <<= 1) {
            float ov = __shfl_xor(bv, m, 64);
            int oi = __shfl_xor(bi, m, 64);
            float osv = __shfl_xor(sv, m, 64);
            bool take = (ov > bv) || (ov == bv && oi < bi);
            float loser = take ? bv : ov;
            bv = take ? ov : bv;
            bi = take ? oi : bi;
            sv = fmaxf(fmaxf(sv, osv), loser);
        }

        if (bv - sv < MARGIN) {  // wave-uniform; rare (~50/32768 rows)
            double bbv = 0.0; int bbi = 0;
            for (int ee = 0; ee < 16; ++ee) {
                double a = 0.0;
#pragma unroll
                for (int k = 0; k < 16; ++k) {
                    const unsigned w32 = pk[k];
                    const int pb = (int)((w32 >> ee) & 1u);
                    const int mb = (int)((w32 >> (16 + ee)) & 1u);
                    a += pb ? (double)xs[k] : (mb ? -(double)xs[k] : 0.0);
                }
#pragma unroll
                for (int m = 1; m < 64; m <<= 1) a += __shfl_xor(a, m, 64);
                if (ee == 0 || a > bbv) { bbv = a; bbi = ee; }
            }
            bi = bbi;
        }

        if (l == 0) {
            idx[row] = bi;
            outIdx[row] = (float)bi;
            atomicAdd(&ctrl[bi * 16], 1u);
        }
    }
}

// Tile-granular prefix: tileBase[e] = #128-row tiles before expert e.
__global__ void k_scan(unsigned* __restrict__ ctrl) {
    if (threadIdx.x == 0) {
        int* tileBase = (int*)(ctrl + 512);
        int acc = 0;
        for (int e = 0; e < NE; ++e) {
            tileBase[e] = acc;
            acc += (int)((ctrl[e * 16] + 127u) / 128u);
        }
        tileBase[NE] = acc;
    }
}

// Perm build: block-aggregated ranks (LDS hist -> 16 global atomics/block).
__global__ __launch_bounds__(256) void k_perm(const int* __restrict__ idx,
                                              unsigned* __restrict__ ctrl,
                                              int* __restrict__ perm) {
    __shared__ unsigned hcnt[16];
    __shared__ unsigned hbase[16];
    const int t = threadIdx.x;
    const int row = blockIdx.x * 256 + t;
    const int* tileBase = (const int*)(ctrl + 512);
    if (t < 16) hcnt[t] = 0;
    __syncthreads();
    const int e = idx[row];
    const unsigned lrank = atomicAdd(&hcnt[e], 1u);
    __syncthreads();
    if (t < 16) hbase[t] = atomicAdd(&ctrl[256 + t * 16], hcnt[t]);
    __syncthreads();
    perm[tileBase[e] * 128 + hbase[e] + lrank] = row;
}

// W f32 -> bf16 (16M elems, 8 per thread).
__global__ __launch_bounds__(256) void k_convw(const float* __restrict__ W,
                                               unsigned short* __restrict__ Wb) {
    const size_t g = ((size_t)blockIdx.x * 256 + threadIdx.x) * 8;
    float4 a = *(const float4*)&W[g];
    float4 b = *(const float4*)&W[g + 4];
    *(ushort4*)&Wb[g]     = make_ushort4(f2bf(a.x), f2bf(a.y), f2bf(a.z), f2bf(a.w));
    *(ushort4*)&Wb[g + 4] = make_ushort4(f2bf(b.x), f2bf(b.y), f2bf(b.z), f2bf(b.w));
}

// Grouped bf16 GEMM: 128x128 tile, BK=32, 4 waves (2x2), 16x16x32 MFMA.
// MODE 0: A gathered from Xbf via perm (per-lane global_load_lds sources),
//         B staged from pre-converted Wb.
// MODE 1 (small ws): reg-staged f32->bf16 conversion from x (via perm) and W.
// Epilogue: +bias, ReLU, +x residual, scatter-store to out rows.
template <int MODE>
__global__ __launch_bounds__(256) void k_gemm(const unsigned short* __restrict__ Xbf,
                                              const unsigned short* __restrict__ Wb,
                                              const float* __restrict__ x,
                                              const float* __restrict__ W,
                                              const float* __restrict__ bias,
                                              const int* __restrict__ perm,
                                              const unsigned* __restrict__ ctrl,
                                              float* __restrict__ out) {
    __shared__ unsigned short A_lds[128 * 32];
    __shared__ unsigned short B_lds[128 * 32];

    const int* tileBase = (const int*)(ctrl + 512);

    // bijective XCD-aware swizzle over NWGX=271 (m204): q=33, r=7
    int bx;
    {
        const int orig = blockIdx.x;
        const int xcd = orig & 7, loc = orig >> 3;
        bx = (xcd < 7 ? xcd * 34 : 238 + (xcd - 7) * 33) + loc;
    }
    const int total = tileBase[NE];
    if (bx >= total) return;
    int e = 0;
    while (e < NE - 1 && tileBase[e + 1] <= bx) ++e;
    const int ltile = bx - tileBase[e];
    const int valid = (int)ctrl[e * 16] - ltile * 128;  // 1..128 valid rows
    const int n0 = blockIdx.y * 128;

    const int t = threadIdx.x, w = t >> 6, l = t & 63;
    const int wr = w >> 1, wc = w & 1;
    const int lc = l & 15, lr = l >> 4;

    f32x4 acc[4][4];
#pragma unroll
    for (int m = 0; m < 4; ++m)
#pragma unroll
        for (int n = 0; n < 4; ++n) acc[m][n] = (f32x4){0.f, 0.f, 0.f, 0.f};

    const size_t aRowBase = (size_t)bx * 128;
    const unsigned short* Bg = Wb + ((size_t)e * DM + n0) * DM;

    // Per-lane gathered A sources (perm prefilled with 0 for pad slots).
    const unsigned short* a0 = nullptr;
    const unsigned short* a1 = nullptr;
    if (MODE == 0) {
        const int r0 = t >> 2;
        const int prow0 = perm[aRowBase + r0];
        const int prow1 = perm[aRowBase + 64 + r0];
        a0 = Xbf + (size_t)prow0 * DM + (t & 3) * 8;
        a1 = Xbf + (size_t)prow1 * DM + (t & 3) * 8;
    }

    for (int kt = 0; kt < DM / 32; ++kt) {
        __syncthreads();
        if (MODE == 0) {
            gload_lds16(a0 + kt * 32, &A_lds[(size_t)(w * 64) * 8]);
            gload_lds16(a1 + kt * 32, &A_lds[(size_t)(256 + w * 64) * 8]);
#pragma unroll
            for (int rd = 0; rd < 2; ++rd) {
                const int c = rd * 256 + t;
                gload_lds16(Bg + (size_t)(c >> 2) * DM + kt * 32 + (c & 3) * 8,
                            &B_lds[(size_t)(rd * 256 + w * 64) * 8]);
            }
        } else {
#pragma unroll
            for (int rd = 0; rd < 2; ++rd) {
                const int c = rd * 256 + t;
                const int r = c >> 2, h = c & 3;
                const float* wp = W + ((size_t)e * DM + n0 + r) * DM + kt * 32 + h * 8;
                float4 b0 = *(const float4*)wp;
                float4 b1 = *(const float4*)(wp + 4);
                *(ushort4*)&B_lds[c * 8]     = make_ushort4(f2bf(b0.x), f2bf(b0.y), f2bf(b0.z), f2bf(b0.w));
                *(ushort4*)&B_lds[c * 8 + 4] = make_ushort4(f2bf(b1.x), f2bf(b1.y), f2bf(b1.z), f2bf(b1.w));
                ushort4 p0 = make_ushort4(0, 0, 0, 0), p1 = p0;
                if (r < valid) {
                    const int orow = perm[aRowBase + r];
                    const float* xp = x + (size_t)orow * DM + kt * 32 + h * 8;
                    float4 q0 = *(const float4*)xp;
                    float4 q1 = *(const float4*)(xp + 4);
                    p0 = make_ushort4(f2bf(q0.x), f2bf(q0.y), f2bf(q0.z), f2bf(q0.w));
                    p1 = make_ushort4(f2bf(q1.x), f2bf(q1.y), f2bf(q1.z), f2bf(q1.w));
                }
                *(ushort4*)&A_lds[c * 8]     = p0;
                *(ushort4*)&A_lds[c * 8 + 4] = p1;
            }
        }
        __syncthreads();

        bf16x8 af[4], bf[4];
#pragma unroll
        for (int m = 0; m < 4; ++m)
            af[m] = *(const bf16x8*)&A_lds[(wr * 64 + m * 16 + lc) * 32 + lr * 8];
#pragma unroll
        for (int n = 0; n < 4; ++n)
            bf[n] = *(const bf16x8*)&B_lds[(wc * 64 + n * 16 + lc) * 32 + lr * 8];
#pragma unroll
        for (int m = 0; m < 4; ++m)
#pragma unroll
            for (int n = 0; n < 4; ++n)
                acc[m][n] = __builtin_amdgcn_mfma_f32_16x16x32_bf16(af[m], bf[n], acc[m][n], 0, 0, 0);
    }

    float bv[4];
#pragma unroll
    for (int n = 0; n < 4; ++n) bv[n] = bias[e * DM + n0 + wc * 64 + n * 16 + lc];

#pragma unroll
    for (int m = 0; m < 4; ++m) {
#pragma unroll
        for (int reg = 0; reg < 4; ++reg) {
            const int rit = wr * 64 + m * 16 + lr * 4 + reg;  // row in tile
            if (rit < valid) {
                const int orow = perm[aRowBase + rit];
                const float* xr = x + (size_t)orow * DM;
                float* op = out + (size_t)orow * DM;
#pragma unroll
                for (int n = 0; n < 4; ++n) {
                    const int col = n0 + wc * 64 + n * 16 + lc;
                    float v = acc[m][n][reg] + bv[n];
                    v = v > 0.f ? v : 0.f;
                    op[col] = v + xr[col];
                }
            }
        }
    }
}

extern "C" void kernel_launch(void* const* d_in, const int* in_sizes, int n_in,
                              void* d_out, int out_size, void* d_ws, size_t ws_size,
                              hipStream_t stream) {
    const float* x    = (const float*)d_in[0];
    const float* sig  = (const float*)d_in[1];
    const float* W    = (const float*)d_in[2];
    const float* bias = (const float*)d_in[3];
    float* out = (float*)d_out;
    float* outIdx = out + (size_t)BATCH * DM;

    char* ws = (char*)d_ws;
    int* idx = (int*)ws;
    unsigned* ctrl = (unsigned*)(ws + CTRL_OFF);
    int* perm = (int*)(ws + PERM_OFF);
    unsigned short* Xbf = (unsigned short*)(ws + XBF_OFF);
    unsigned short* Wb = (unsigned short*)(ws + WB_OFF);

    const bool full = ws_size >= WS_NEED;

    k_init<<<40, 256, 0, stream>>>(sig, ctrl, perm);
    k_router<<<2048, 256, 0, stream>>>(x, ctrl, idx, outIdx, Xbf, full ? 1 : 0);
    k_scan<<<1, 64, 0, stream>>>(ctrl);
    k_perm<<<128, 256, 0, stream>>>(idx, ctrl, perm);
    if (full) {
        k_convw<<<8192, 256, 0, stream>>>(W, Wb);
        k_gemm<0><<<dim3(271, 8), 256, 0, stream>>>(Xbf, Wb, x, W, bias, perm, ctrl, out);
    } else {
        k_gemm<1><<<dim3(271, 8), 256, 0, stream>>>(Xbf, Wb, x, W, bias, perm, ctrl, out);
    }
}

// Round 4
// 297.000 us; speedup vs baseline: 3.6117x; 1.2581x over previous
//
#include <hip/hip_runtime.h>
#include <hip/hip_bf16.h>

#define BATCH   32768
#define DM      1024
#define NE      16
#define THRESHF 0.3f
#define MARGIN  0.02f

// ws layout (bytes)
// idx   @ 0          : int32[32768]            = 131072
// ctrl  @ 131072     : u32[2048] (8192 B)
//    [e*16]        counts (one 64B line per expert)
//    [256 + e*16]  cursor (strided)
//    [512..528]    tileBase int[17]
//    [1024..2047]  packT u32[1024] (pm | mm<<16 per dim)
// Qbf   @ 139264     : bf16[16*1024] ternary   = 32768
// perm  @ 172032     : int32[34816]            (prefilled 0 for pad slots)
// Xbf   @ 311296     : bf16[32768*1024]        = 67108864
// Wb    @ 67420160   : bf16[16*1024*1024]      = 33554432   (ends ~96.3 MB)
#define CTRL_OFF 131072
#define QBF_OFF  139264
#define PERM_OFF 172032
#define XBF_OFF  311296
#define WB_OFF   67420160ull
#define WS_NEED  (WB_OFF + (size_t)NE * DM * DM * 2)

typedef __attribute__((ext_vector_type(8))) short bf16x8;
typedef __attribute__((ext_vector_type(4))) float f32x4;

static __device__ __forceinline__ unsigned short f2bf(float f) {
    union { float f; unsigned u; } v; v.f = f;
    unsigned r = (v.u + 0x7FFFu + ((v.u >> 16) & 1u)) >> 16;  // RNE
    return (unsigned short)r;
}
static __device__ __forceinline__ float bf2f(unsigned short h) {
    union { unsigned u; float f; } v; v.u = ((unsigned)h) << 16;
    return v.f;
}

static __device__ __forceinline__ void gload_lds16(const void* g, void* s) {
    __builtin_amdgcn_global_load_lds(
        (const __attribute__((address_space(1))) void*)g,
        (__attribute__((address_space(3))) void*)s, 16, 0, 0);
}

// Zero ctrl, build ternary pack table + bf16 ternary Q, prefill perm with 0.
// 64 blocks x 256 -> t = 0..16383.
__global__ void k_init(const float* __restrict__ sig, unsigned* __restrict__ ctrl,
                       int* __restrict__ perm, unsigned short* __restrict__ Qbf) {
    const int t = blockIdx.x * 256 + threadIdx.x;
    if (t < 544) ctrl[t] = 0;
    if (t < 1024) {
        unsigned pm = 0, mm = 0;
#pragma unroll
        for (int e = 0; e < NE; ++e) {
            float s = sig[e * DM + t];
            pm |= (s > THRESHF ? 1u : 0u) << e;
            mm |= (s < -THRESHF ? 1u : 0u) << e;
        }
        ctrl[1024 + t] = pm | (mm << 16);
    }
    if (t < 8704) ((int4*)perm)[t] = make_int4(0, 0, 0, 0);
    {   // Qbf[e][d], t = e*1024+d
        float s = sig[t];
        Qbf[t] = s > THRESHF ? (unsigned short)0x3F80u
                             : (s < -THRESHF ? (unsigned short)0xBF80u : (unsigned short)0u);
    }
}

// MFMA router: scores = (x_hi @ Q^T) + (x_lo @ Q^T) in bf16 MFMA (f32 acc),
// top-2 margin; exact f64 fallback for close calls; writes Xbf (= x_hi).
// 512 blocks x 4 waves; each wave owns 16 rows; no LDS, no barriers.
__global__ __launch_bounds__(256) void k_router(const float* __restrict__ x,
                                                const unsigned short* __restrict__ Qbf,
                                                unsigned* __restrict__ ctrl,
                                                int* __restrict__ idx,
                                                float* __restrict__ outIdx,
                                                unsigned short* __restrict__ Xbf,
                                                int writeXbf) {
    const int t = threadIdx.x, w = t >> 6, l = t & 63;
    const int lc = l & 15, lr = l >> 4;
    const int wid = blockIdx.x * 4 + w;   // 0..2047
    const int row0 = wid * 16;
    const unsigned* packT = ctrl + 1024;

    const float* ax = x + (size_t)(row0 + lc) * DM + lr * 8;
    const unsigned short* qx = Qbf + (size_t)lc * DM + lr * 8;
    unsigned short* xb = Xbf + (size_t)(row0 + lc) * DM + lr * 8;

    f32x4 acc = (f32x4){0.f, 0.f, 0.f, 0.f};

    for (int kt = 0; kt < 16; ++kt) {
#pragma unroll
        for (int h = 0; h < 2; ++h) {
            const int ko = kt * 64 + h * 32;
            float4 v0 = *(const float4*)(ax + ko);
            float4 v1 = *(const float4*)(ax + ko + 4);
            bf16x8 q = *(const bf16x8*)(qx + ko);

            float f[8] = {v0.x, v0.y, v0.z, v0.w, v1.x, v1.y, v1.z, v1.w};
            bf16x8 ah, al;
#pragma unroll
            for (int j = 0; j < 8; ++j) {
                unsigned short hi = f2bf(f[j]);
                float r = f[j] - bf2f(hi);
                ah[j] = (short)hi;
                al[j] = (short)f2bf(r);
            }
            if (writeXbf) *(bf16x8*)(xb + ko) = ah;
            acc = __builtin_amdgcn_mfma_f32_16x16x32_bf16(ah, q, acc, 0, 0, 0);
            acc = __builtin_amdgcn_mfma_f32_16x16x32_bf16(al, q, acc, 0, 0, 0);
        }
    }
    // C layout: lane holds scores of expert e=lc for rows lr*4+reg.

    float bv[4]; int bi[4]; float gap[4];
#pragma unroll
    for (int reg = 0; reg < 4; ++reg) {
        float v = acc[reg]; int i = lc; float s = -3.4e38f;
#pragma unroll
        for (int m = 1; m < 16; m <<= 1) {
            float ov = __shfl_xor(v, m, 64);
            int oi = __shfl_xor(i, m, 64);
            float os = __shfl_xor(s, m, 64);
            bool take = (ov > v) || (ov == v && oi < i);
            float loser = take ? v : ov;
            v = take ? ov : v;
            i = take ? oi : i;
            s = fmaxf(fmaxf(s, os), loser);
        }
        bv[reg] = v; bi[reg] = i; gap[reg] = v - s;
    }

    unsigned flagsw = 0;
#pragma unroll
    for (int reg = 0; reg < 4; ++reg)
        flagsw |= (gap[reg] < MARGIN ? 1u : 0u) << reg;

    if (__any(lc == 0 && flagsw != 0)) {   // rare exact path
#pragma unroll
        for (int reg = 0; reg < 4; ++reg) {
            for (int g = 0; g < 4; ++g) {
                const unsigned fw = __shfl(flagsw, g * 16, 64);
                if ((fw >> reg) & 1u) {
                    const int row = row0 + g * 4 + reg;
                    const float* xr = x + (size_t)row * DM;
                    float xv[16]; unsigned mk[16];
#pragma unroll
                    for (int k2 = 0; k2 < 16; ++k2) {
                        xv[k2] = xr[k2 * 64 + l];
                        mk[k2] = packT[k2 * 64 + l];
                    }
                    double best = 0.0; int bbi = 0;
                    for (int e = 0; e < 16; ++e) {
                        double a = 0.0;
#pragma unroll
                        for (int k2 = 0; k2 < 16; ++k2) {
                            const int pb = (int)((mk[k2] >> e) & 1u);
                            const int mb = (int)((mk[k2] >> (16 + e)) & 1u);
                            a += pb ? (double)xv[k2] : (mb ? -(double)xv[k2] : 0.0);
                        }
#pragma unroll
                        for (int m = 1; m < 64; m <<= 1) a += __shfl_xor(a, m, 64);
                        if (e == 0 || a > best) { best = a; bbi = e; }
                    }
                    if (lr == g && lc == 0) bi[reg] = bbi;
                }
            }
        }
    }

    if (lc == 0) {
#pragma unroll
        for (int reg = 0; reg < 4; ++reg) {
            const int row = row0 + lr * 4 + reg;
            idx[row] = bi[reg];
            outIdx[row] = (float)bi[reg];
            atomicAdd(&ctrl[bi[reg] * 16], 1u);
        }
    }
}

// Tile-granular prefix: tileBase[e] = #128-row tiles before expert e.
__global__ void k_scan(unsigned* __restrict__ ctrl) {
    if (threadIdx.x == 0) {
        int* tileBase = (int*)(ctrl + 512);
        int acc = 0;
        for (int e = 0; e < NE; ++e) {
            tileBase[e] = acc;
            acc += (int)((ctrl[e * 16] + 127u) / 128u);
        }
        tileBase[NE] = acc;
    }
}

// Perm build: block-aggregated ranks (LDS hist -> 16 global atomics/block).
__global__ __launch_bounds__(256) void k_perm(const int* __restrict__ idx,
                                              unsigned* __restrict__ ctrl,
                                              int* __restrict__ perm) {
    __shared__ unsigned hcnt[16];
    __shared__ unsigned hbase[16];
    const int t = threadIdx.x;
    const int row = blockIdx.x * 256 + t;
    const int* tileBase = (const int*)(ctrl + 512);
    if (t < 16) hcnt[t] = 0;
    __syncthreads();
    const int e = idx[row];
    const unsigned lrank = atomicAdd(&hcnt[e], 1u);
    __syncthreads();
    if (t < 16) hbase[t] = atomicAdd(&ctrl[256 + t * 16], hcnt[t]);
    __syncthreads();
    perm[tileBase[e] * 128 + hbase[e] + lrank] = row;
}

// W f32 -> bf16 (16M elems, 8 per thread).
__global__ __launch_bounds__(256) void k_convw(const float* __restrict__ W,
                                               unsigned short* __restrict__ Wb) {
    const size_t g = ((size_t)blockIdx.x * 256 + threadIdx.x) * 8;
    float4 a = *(const float4*)&W[g];
    float4 b = *(const float4*)&W[g + 4];
    *(ushort4*)&Wb[g]     = make_ushort4(f2bf(a.x), f2bf(a.y), f2bf(a.z), f2bf(a.w));
    *(ushort4*)&Wb[g + 4] = make_ushort4(f2bf(b.x), f2bf(b.y), f2bf(b.z), f2bf(b.w));
}

// Grouped bf16 GEMM: 128x128 tile, BK=32, 4 waves (2x2), 16x16x32 MFMA.
// MODE 0: A gathered from Xbf via perm (per-lane global_load_lds sources),
//         B staged from pre-converted Wb.
// MODE 1 (small ws): reg-staged f32->bf16 conversion from x (via perm) and W.
// Epilogue: +bias, ReLU, +x residual, scatter-store to out rows.
template <int MODE>
__global__ __launch_bounds__(256) void k_gemm(const unsigned short* __restrict__ Xbf,
                                              const unsigned short* __restrict__ Wb,
                                              const float* __restrict__ x,
                                              const float* __restrict__ W,
                                              const float* __restrict__ bias,
                                              const int* __restrict__ perm,
                                              const unsigned* __restrict__ ctrl,
                                              float* __restrict__ out) {
    __shared__ unsigned short A_lds[128 * 32];
    __shared__ unsigned short B_lds[128 * 32];

    const int* tileBase = (const int*)(ctrl + 512);

    // bijective XCD-aware swizzle over NWGX=271 (m204): q=33, r=7
    int bx;
    {
        const int orig = blockIdx.x;
        const int xcd = orig & 7, loc = orig >> 3;
        bx = (xcd < 7 ? xcd * 34 : 238 + (xcd - 7) * 33) + loc;
    }
    const int total = tileBase[NE];
    if (bx >= total) return;
    int e = 0;
    while (e < NE - 1 && tileBase[e + 1] <= bx) ++e;
    const int ltile = bx - tileBase[e];
    const int valid = (int)ctrl[e * 16] - ltile * 128;  // 1..128 valid rows
    const int n0 = blockIdx.y * 128;

    const int t = threadIdx.x, w = t >> 6, l = t & 63;
    const int wr = w >> 1, wc = w & 1;
    const int lc = l & 15, lr = l >> 4;

    f32x4 acc[4][4];
#pragma unroll
    for (int m = 0; m < 4; ++m)
#pragma unroll
        for (int n = 0; n < 4; ++n) acc[m][n] = (f32x4){0.f, 0.f, 0.f, 0.f};

    const size_t aRowBase = (size_t)bx * 128;
    const unsigned short* Bg = Wb + ((size_t)e * DM + n0) * DM;

    // Per-lane gathered A sources (perm prefilled with 0 for pad slots).
    const unsigned short* a0 = nullptr;
    const unsigned short* a1 = nullptr;
    if (MODE == 0) {
        const int r0 = t >> 2;
        const int prow0 = perm[aRowBase + r0];
        const int prow1 = perm[aRowBase + 64 + r0];
        a0 = Xbf + (size_t)prow0 * DM + (t & 3) * 8;
        a1 = Xbf + (size_t)prow1 * DM + (t & 3) * 8;
    }

    for (int kt = 0; kt < DM / 32; ++kt) {
        __syncthreads();
        if (MODE == 0) {
            gload_lds16(a0 + kt * 32, &A_lds[(size_t)(w * 64) * 8]);
            gload_lds16(a1 + kt * 32, &A_lds[(size_t)(256 + w * 64) * 8]);
#pragma unroll
            for (int rd = 0; rd < 2; ++rd) {
                const int c = rd * 256 + t;
                gload_lds16(Bg + (size_t)(c >> 2) * DM + kt * 32 + (c & 3) * 8,
                            &B_lds[(size_t)(rd * 256 + w * 64) * 8]);
            }
        } else {
#pragma unroll
            for (int rd = 0; rd < 2; ++rd) {
                const int c = rd * 256 + t;
                const int r = c >> 2, h = c & 3;
                const float* wp = W + ((size_t)e * DM + n0 + r) * DM + kt * 32 + h * 8;
                float4 b0 = *(const float4*)wp;
                float4 b1 = *(const float4*)(wp + 4);
                *(ushort4*)&B_lds[c * 8]     = make_ushort4(f2bf(b0.x), f2bf(b0.y), f2bf(b0.z), f2bf(b0.w));
                *(ushort4*)&B_lds[c * 8 + 4] = make_ushort4(f2bf(b1.x), f2bf(b1.y), f2bf(b1.z), f2bf(b1.w));
                ushort4 p0 = make_ushort4(0, 0, 0, 0), p1 = p0;
                if (r < valid) {
                    const int orow = perm[aRowBase + r];
                    const float* xp = x + (size_t)orow * DM + kt * 32 + h * 8;
                    float4 q0 = *(const float4*)xp;
                    float4 q1 = *(const float4*)(xp + 4);
                    p0 = make_ushort4(f2bf(q0.x), f2bf(q0.y), f2bf(q0.z), f2bf(q0.w));
                    p1 = make_ushort4(f2bf(q1.x), f2bf(q1.y), f2bf(q1.z), f2bf(q1.w));
                }
                *(ushort4*)&A_lds[c * 8]     = p0;
                *(ushort4*)&A_lds[c * 8 + 4] = p1;
            }
        }
        __syncthreads();

        bf16x8 af[4], bf[4];
#pragma unroll
        for (int m = 0; m < 4; ++m)
            af[m] = *(const bf16x8*)&A_lds[(wr * 64 + m * 16 + lc) * 32 + lr * 8];
#pragma unroll
        for (int n = 0; n < 4; ++n)
            bf[n] = *(const bf16x8*)&B_lds[(wc * 64 + n * 16 + lc) * 32 + lr * 8];
#pragma unroll
        for (int m = 0; m < 4; ++m)
#pragma unroll
            for (int n = 0; n < 4; ++n)
                acc[m][n] = __builtin_amdgcn_mfma_f32_16x16x32_bf16(af[m], bf[n], acc[m][n], 0, 0, 0);
    }

    float bv[4];
#pragma unroll
    for (int n = 0; n < 4; ++n) bv[n] = bias[e * DM + n0 + wc * 64 + n * 16 + lc];

#pragma unroll
    for (int m = 0; m < 4; ++m) {
#pragma unroll
        for (int reg = 0; reg < 4; ++reg) {
            const int rit = wr * 64 + m * 16 + lr * 4 + reg;  // row in tile
            if (rit < valid) {
                const int orow = perm[aRowBase + rit];
                const float* xr = x + (size_t)orow * DM;
                float* op = out + (size_t)orow * DM;
#pragma unroll
                for (int n = 0; n < 4; ++n) {
                    const int col = n0 + wc * 64 + n * 16 + lc;
                    float v = acc[m][n][reg] + bv[n];
                    v = v > 0.f ? v : 0.f;
                    op[col] = v + xr[col];
                }
            }
        }
    }
}

extern "C" void kernel_launch(void* const* d_in, const int* in_sizes, int n_in,
                              void* d_out, int out_size, void* d_ws, size_t ws_size,
                              hipStream_t stream) {
    const float* x    = (const float*)d_in[0];
    const float* sig  = (const float*)d_in[1];
    const float* W    = (const float*)d_in[2];
    const float* bias = (const float*)d_in[3];
    float* out = (float*)d_out;
    float* outIdx = out + (size_t)BATCH * DM;

    char* ws = (char*)d_ws;
    int* idx = (int*)ws;
    unsigned* ctrl = (unsigned*)(ws + CTRL_OFF);
    unsigned short* Qbf = (unsigned short*)(ws + QBF_OFF);
    int* perm = (int*)(ws + PERM_OFF);
    unsigned short* Xbf = (unsigned short*)(ws + XBF_OFF);
    unsigned short* Wb = (unsigned short*)(ws + WB_OFF);

    const bool full = ws_size >= WS_NEED;

    k_init<<<64, 256, 0, stream>>>(sig, ctrl, perm, Qbf);
    k_router<<<512, 256, 0, stream>>>(x, Qbf, ctrl, idx, outIdx, Xbf, full ? 1 : 0);
    k_scan<<<1, 64, 0, stream>>>(ctrl);
    k_perm<<<128, 256, 0, stream>>>(idx, ctrl, perm);
    if (full) {
        k_convw<<<8192, 256, 0, stream>>>(W, Wb);
        k_gemm<0><<<dim3(271, 8), 256, 0, stream>>>(Xbf, Wb, x, W, bias, perm, ctrl, out);
    } else {
        k_gemm<1><<<dim3(271, 8), 256, 0, stream>>>(Xbf, Wb, x, W, bias, perm, ctrl, out);
    }
}

// Round 5
// 253.144 us; speedup vs baseline: 4.2374x; 1.1732x over previous
//
#include <hip/hip_runtime.h>
#include <hip/hip_bf16.h>

#define BATCH   32768
#define DM      1024
#define NE      16
#define THRESHF 0.3f
#define MARGIN  0.02f

// ws layout (bytes)
// idx   @ 0          : int32[32768]            = 131072
// ctrl  @ 131072     : u32[2048] (8192 B)
//    [e*16]        counts (one 64B line per expert)
//    [256 + e*16]  cursor (strided)
//    [512..528]    tileBase int[17]
//    [1024..2047]  packT u32[1024] (pm | mm<<16 per dim)
// Qbf   @ 139264     : bf16[16*1024] ternary   = 32768
// perm  @ 172032     : int32[34816]            (prefilled 0 for pad slots)
// Xbf   @ 311296     : bf16[32768*1024]        = 67108864
// Wb    @ 67420160   : bf16[16*1024*1024]      = 33554432   (ends ~96.3 MB)
#define CTRL_OFF 131072
#define QBF_OFF  139264
#define PERM_OFF 172032
#define XBF_OFF  311296
#define WB_OFF   67420160ull
#define WS_NEED  (WB_OFF + (size_t)NE * DM * DM * 2)

typedef __attribute__((ext_vector_type(8))) short bf16x8;
typedef __attribute__((ext_vector_type(4))) float f32x4;

static __device__ __forceinline__ unsigned short f2bf(float f) {
    union { float f; unsigned u; } v; v.f = f;
    unsigned r = (v.u + 0x7FFFu + ((v.u >> 16) & 1u)) >> 16;  // RNE
    return (unsigned short)r;
}
static __device__ __forceinline__ float bf2f(unsigned short h) {
    union { unsigned u; float f; } v; v.u = ((unsigned)h) << 16;
    return v.f;
}

static __device__ __forceinline__ void gload_lds16(const void* g, void* s) {
    __builtin_amdgcn_global_load_lds(
        (const __attribute__((address_space(1))) void*)g,
        (__attribute__((address_space(3))) void*)s, 16, 0, 0);
}

// Zero ctrl, build ternary pack table + bf16 ternary Q, prefill perm with 0.
// 64 blocks x 256 -> t = 0..16383.
__global__ void k_init(const float* __restrict__ sig, unsigned* __restrict__ ctrl,
                       int* __restrict__ perm, unsigned short* __restrict__ Qbf) {
    const int t = blockIdx.x * 256 + threadIdx.x;
    if (t < 544) ctrl[t] = 0;
    if (t < 1024) {
        unsigned pm = 0, mm = 0;
#pragma unroll
        for (int e = 0; e < NE; ++e) {
            float s = sig[e * DM + t];
            pm |= (s > THRESHF ? 1u : 0u) << e;
            mm |= (s < -THRESHF ? 1u : 0u) << e;
        }
        ctrl[1024 + t] = pm | (mm << 16);
    }
    if (t < 8704) ((int4*)perm)[t] = make_int4(0, 0, 0, 0);
    {   // Qbf[e][d], t = e*1024+d
        float s = sig[t];
        Qbf[t] = s > THRESHF ? (unsigned short)0x3F80u
                             : (s < -THRESHF ? (unsigned short)0xBF80u : (unsigned short)0u);
    }
}

// MFMA router: scores = (x_hi @ Q^T) + (x_lo @ Q^T) in bf16 MFMA (f32 acc),
// top-2 margin; exact f64 fallback for close calls; writes Xbf (= x_hi).
__global__ __launch_bounds__(256) void k_router(const float* __restrict__ x,
                                                const unsigned short* __restrict__ Qbf,
                                                unsigned* __restrict__ ctrl,
                                                int* __restrict__ idx,
                                                float* __restrict__ outIdx,
                                                unsigned short* __restrict__ Xbf,
                                                int writeXbf) {
    const int t = threadIdx.x, w = t >> 6, l = t & 63;
    const int lc = l & 15, lr = l >> 4;
    const int wid = blockIdx.x * 4 + w;   // 0..2047
    const int row0 = wid * 16;
    const unsigned* packT = ctrl + 1024;

    const float* ax = x + (size_t)(row0 + lc) * DM + lr * 8;
    const unsigned short* qx = Qbf + (size_t)lc * DM + lr * 8;
    unsigned short* xb = Xbf + (size_t)(row0 + lc) * DM + lr * 8;

    f32x4 acc = (f32x4){0.f, 0.f, 0.f, 0.f};

    for (int kt = 0; kt < 16; ++kt) {
#pragma unroll
        for (int h = 0; h < 2; ++h) {
            const int ko = kt * 64 + h * 32;
            float4 v0 = *(const float4*)(ax + ko);
            float4 v1 = *(const float4*)(ax + ko + 4);
            bf16x8 q = *(const bf16x8*)(qx + ko);

            float f[8] = {v0.x, v0.y, v0.z, v0.w, v1.x, v1.y, v1.z, v1.w};
            bf16x8 ah, al;
#pragma unroll
            for (int j = 0; j < 8; ++j) {
                unsigned short hi = f2bf(f[j]);
                float r = f[j] - bf2f(hi);
                ah[j] = (short)hi;
                al[j] = (short)f2bf(r);
            }
            if (writeXbf) *(bf16x8*)(xb + ko) = ah;
            acc = __builtin_amdgcn_mfma_f32_16x16x32_bf16(ah, q, acc, 0, 0, 0);
            acc = __builtin_amdgcn_mfma_f32_16x16x32_bf16(al, q, acc, 0, 0, 0);
        }
    }
    // C layout: lane holds scores of expert e=lc for rows lr*4+reg.

    float bv[4]; int bi[4]; float gap[4];
#pragma unroll
    for (int reg = 0; reg < 4; ++reg) {
        float v = acc[reg]; int i = lc; float s = -3.4e38f;
#pragma unroll
        for (int m = 1; m < 16; m <<= 1) {
            float ov = __shfl_xor(v, m, 64);
            int oi = __shfl_xor(i, m, 64);
            float os = __shfl_xor(s, m, 64);
            bool take = (ov > v) || (ov == v && oi < i);
            float loser = take ? v : ov;
            v = take ? ov : v;
            i = take ? oi : i;
            s = fmaxf(fmaxf(s, os), loser);
        }
        bv[reg] = v; bi[reg] = i; gap[reg] = v - s;
    }

    unsigned flagsw = 0;
#pragma unroll
    for (int reg = 0; reg < 4; ++reg)
        flagsw |= (gap[reg] < MARGIN ? 1u : 0u) << reg;

    if (__any(lc == 0 && flagsw != 0)) {   // rare exact path
#pragma unroll
        for (int reg = 0; reg < 4; ++reg) {
            for (int g = 0; g < 4; ++g) {
                const unsigned fw = __shfl(flagsw, g * 16, 64);
                if ((fw >> reg) & 1u) {
                    const int row = row0 + g * 4 + reg;
                    const float* xr = x + (size_t)row * DM;
                    float xv[16]; unsigned mk[16];
#pragma unroll
                    for (int k2 = 0; k2 < 16; ++k2) {
                        xv[k2] = xr[k2 * 64 + l];
                        mk[k2] = packT[k2 * 64 + l];
                    }
                    double best = 0.0; int bbi = 0;
                    for (int e = 0; e < 16; ++e) {
                        double a = 0.0;
#pragma unroll
                        for (int k2 = 0; k2 < 16; ++k2) {
                            const int pb = (int)((mk[k2] >> e) & 1u);
                            const int mb = (int)((mk[k2] >> (16 + e)) & 1u);
                            a += pb ? (double)xv[k2] : (mb ? -(double)xv[k2] : 0.0);
                        }
#pragma unroll
                        for (int m = 1; m < 64; m <<= 1) a += __shfl_xor(a, m, 64);
                        if (e == 0 || a > best) { best = a; bbi = e; }
                    }
                    if (lr == g && lc == 0) bi[reg] = bbi;
                }
            }
        }
    }

    if (lc == 0) {
#pragma unroll
        for (int reg = 0; reg < 4; ++reg) {
            const int row = row0 + lr * 4 + reg;
            idx[row] = bi[reg];
            outIdx[row] = (float)bi[reg];
            atomicAdd(&ctrl[bi[reg] * 16], 1u);
        }
    }
}

// Tile-granular prefix: tileBase[e] = #128-row tiles before expert e.
__global__ void k_scan(unsigned* __restrict__ ctrl) {
    if (threadIdx.x == 0) {
        int* tileBase = (int*)(ctrl + 512);
        int acc = 0;
        for (int e = 0; e < NE; ++e) {
            tileBase[e] = acc;
            acc += (int)((ctrl[e * 16] + 127u) / 128u);
        }
        tileBase[NE] = acc;
    }
}

// Perm build: block-aggregated ranks (LDS hist -> 16 global atomics/block).
__global__ __launch_bounds__(256) void k_perm(const int* __restrict__ idx,
                                              unsigned* __restrict__ ctrl,
                                              int* __restrict__ perm) {
    __shared__ unsigned hcnt[16];
    __shared__ unsigned hbase[16];
    const int t = threadIdx.x;
    const int row = blockIdx.x * 256 + t;
    const int* tileBase = (const int*)(ctrl + 512);
    if (t < 16) hcnt[t] = 0;
    __syncthreads();
    const int e = idx[row];
    const unsigned lrank = atomicAdd(&hcnt[e], 1u);
    __syncthreads();
    if (t < 16) hbase[t] = atomicAdd(&ctrl[256 + t * 16], hcnt[t]);
    __syncthreads();
    perm[tileBase[e] * 128 + hbase[e] + lrank] = row;
}

// W f32 -> bf16 (16M elems, 8 per thread).
__global__ __launch_bounds__(256) void k_convw(const float* __restrict__ W,
                                               unsigned short* __restrict__ Wb) {
    const size_t g = ((size_t)blockIdx.x * 256 + threadIdx.x) * 8;
    float4 a = *(const float4*)&W[g];
    float4 b = *(const float4*)&W[g + 4];
    *(ushort4*)&Wb[g]     = make_ushort4(f2bf(a.x), f2bf(a.y), f2bf(a.z), f2bf(a.w));
    *(ushort4*)&Wb[g + 4] = make_ushort4(f2bf(b.x), f2bf(b.y), f2bf(b.z), f2bf(b.w));
}

// Grouped bf16 GEMM: 128x128 tile, BK=32, 4 waves (2x2), 16x16x32 MFMA.
// MODE 0: double-buffered LDS, stage-ahead (one barrier per K-step);
//         A gathered from Xbf via perm (per-lane global_load_lds sources),
//         B from pre-converted Wb. 1-D grid, XCD-local (bx, ny) decode:
//         the 8 ny-siblings of one bx share an XCD's L2 (A panel + expert B).
// MODE 1 (small ws): reg-staged f32->bf16 conversion from x and W.
// Epilogue: +bias, ReLU, +bf16 residual from Xbf, scatter-store to out rows.
template <int MODE>
__global__ __launch_bounds__(256) void k_gemm(const unsigned short* __restrict__ Xbf,
                                              const unsigned short* __restrict__ Wb,
                                              const float* __restrict__ x,
                                              const float* __restrict__ W,
                                              const float* __restrict__ bias,
                                              const int* __restrict__ perm,
                                              const unsigned* __restrict__ ctrl,
                                              float* __restrict__ out) {
    __shared__ unsigned short A_lds[2][128 * 32];
    __shared__ unsigned short B_lds[2][128 * 32];

    const int* tileBase = (const int*)(ctrl + 512);

    // flat = 0..2175: xcd = flat&7 (round-robin dispatch), per-XCD slot s2 =
    // flat>>3 (0..271); bx = xcd*34 + (s2>>3), ny = s2&7  -> bijective, and
    // all 8 ny-siblings of a bx land on the same XCD, adjacent in dispatch.
    int bx, ny;
    {
        const int flat = blockIdx.x;
        const int xcd = flat & 7, s2 = flat >> 3;
        bx = xcd * 34 + (s2 >> 3);
        ny = s2 & 7;
    }
    const int total = tileBase[NE];
    if (bx >= total) return;
    int e = 0;
    while (e < NE - 1 && tileBase[e + 1] <= bx) ++e;
    const int ltile = bx - tileBase[e];
    const int valid = (int)ctrl[e * 16] - ltile * 128;  // 1..128 valid rows
    const int n0 = ny * 128;

    const int t = threadIdx.x, w = t >> 6, l = t & 63;
    const int wr = w >> 1, wc = w & 1;
    const int lc = l & 15, lr = l >> 4;

    f32x4 acc[4][4];
#pragma unroll
    for (int m = 0; m < 4; ++m)
#pragma unroll
        for (int n = 0; n < 4; ++n) acc[m][n] = (f32x4){0.f, 0.f, 0.f, 0.f};

    const size_t aRowBase = (size_t)bx * 128;
    const unsigned short* Bg = Wb + ((size_t)e * DM + n0) * DM;

    if (MODE == 0) {
        // Per-lane gathered A sources (perm prefilled 0 for pad slots).
        const int r0 = t >> 2;
        const int prow0 = perm[aRowBase + r0];
        const int prow1 = perm[aRowBase + 64 + r0];
        const unsigned short* a0 = Xbf + (size_t)prow0 * DM + (t & 3) * 8;
        const unsigned short* a1 = Xbf + (size_t)prow1 * DM + (t & 3) * 8;

        // prologue: stage tile 0 into buf 0
        gload_lds16(a0, &A_lds[0][(size_t)(w * 64) * 8]);
        gload_lds16(a1, &A_lds[0][(size_t)(256 + w * 64) * 8]);
#pragma unroll
        for (int rd = 0; rd < 2; ++rd) {
            const int c = rd * 256 + t;
            gload_lds16(Bg + (size_t)(c >> 2) * DM + (c & 3) * 8,
                        &B_lds[0][(size_t)(rd * 256 + w * 64) * 8]);
        }
        __syncthreads();

        int cur = 0;
        for (int kt = 0; kt < DM / 32; ++kt) {
            if (kt < DM / 32 - 1) {  // stage-ahead: next tile into buf^1
                const int ko = (kt + 1) * 32;
                gload_lds16(a0 + ko, &A_lds[cur ^ 1][(size_t)(w * 64) * 8]);
                gload_lds16(a1 + ko, &A_lds[cur ^ 1][(size_t)(256 + w * 64) * 8]);
#pragma unroll
                for (int rd = 0; rd < 2; ++rd) {
                    const int c = rd * 256 + t;
                    gload_lds16(Bg + (size_t)(c >> 2) * DM + ko + (c & 3) * 8,
                                &B_lds[cur ^ 1][(size_t)(rd * 256 + w * 64) * 8]);
                }
            }

            bf16x8 af[4], bf[4];
#pragma unroll
            for (int m = 0; m < 4; ++m)
                af[m] = *(const bf16x8*)&A_lds[cur][(wr * 64 + m * 16 + lc) * 32 + lr * 8];
#pragma unroll
            for (int n = 0; n < 4; ++n)
                bf[n] = *(const bf16x8*)&B_lds[cur][(wc * 64 + n * 16 + lc) * 32 + lr * 8];
#pragma unroll
            for (int m = 0; m < 4; ++m)
#pragma unroll
                for (int n = 0; n < 4; ++n)
                    acc[m][n] = __builtin_amdgcn_mfma_f32_16x16x32_bf16(af[m], bf[n], acc[m][n], 0, 0, 0);

            if (kt < DM / 32 - 1) __syncthreads();  // vmcnt(0)+barrier: buf^1 ready
            cur ^= 1;
        }
    } else {
        for (int kt = 0; kt < DM / 32; ++kt) {
            __syncthreads();
#pragma unroll
            for (int rd = 0; rd < 2; ++rd) {
                const int c = rd * 256 + t;
                const int r = c >> 2, h = c & 3;
                const float* wp = W + ((size_t)e * DM + n0 + r) * DM + kt * 32 + h * 8;
                float4 b0 = *(const float4*)wp;
                float4 b1 = *(const float4*)(wp + 4);
                *(ushort4*)&B_lds[0][c * 8]     = make_ushort4(f2bf(b0.x), f2bf(b0.y), f2bf(b0.z), f2bf(b0.w));
                *(ushort4*)&B_lds[0][c * 8 + 4] = make_ushort4(f2bf(b1.x), f2bf(b1.y), f2bf(b1.z), f2bf(b1.w));
                ushort4 p0 = make_ushort4(0, 0, 0, 0), p1 = p0;
                if (r < valid) {
                    const int orow = perm[aRowBase + r];
                    const float* xp = x + (size_t)orow * DM + kt * 32 + h * 8;
                    float4 q0 = *(const float4*)xp;
                    float4 q1 = *(const float4*)(xp + 4);
                    p0 = make_ushort4(f2bf(q0.x), f2bf(q0.y), f2bf(q0.z), f2bf(q0.w));
                    p1 = make_ushort4(f2bf(q1.x), f2bf(q1.y), f2bf(q1.z), f2bf(q1.w));
                }
                *(ushort4*)&A_lds[0][c * 8]     = p0;
                *(ushort4*)&A_lds[0][c * 8 + 4] = p1;
            }
            __syncthreads();

            bf16x8 af[4], bf[4];
#pragma unroll
            for (int m = 0; m < 4; ++m)
                af[m] = *(const bf16x8*)&A_lds[0][(wr * 64 + m * 16 + lc) * 32 + lr * 8];
#pragma unroll
            for (int n = 0; n < 4; ++n)
                bf[n] = *(const bf16x8*)&B_lds[0][(wc * 64 + n * 16 + lc) * 32 + lr * 8];
#pragma unroll
            for (int m = 0; m < 4; ++m)
#pragma unroll
                for (int n = 0; n < 4; ++n)
                    acc[m][n] = __builtin_amdgcn_mfma_f32_16x16x32_bf16(af[m], bf[n], acc[m][n], 0, 0, 0);
        }
    }

    float bv[4];
#pragma unroll
    for (int n = 0; n < 4; ++n) bv[n] = bias[e * DM + n0 + wc * 64 + n * 16 + lc];

#pragma unroll
    for (int m = 0; m < 4; ++m) {
#pragma unroll
        for (int reg = 0; reg < 4; ++reg) {
            const int rit = wr * 64 + m * 16 + lr * 4 + reg;  // row in tile
            if (rit < valid) {
                const int orow = perm[aRowBase + rit];
                float* op = out + (size_t)orow * DM;
                if (MODE == 0) {
                    const unsigned short* xr = Xbf + (size_t)orow * DM;
#pragma unroll
                    for (int n = 0; n < 4; ++n) {
                        const int col = n0 + wc * 64 + n * 16 + lc;
                        float v = acc[m][n][reg] + bv[n];
                        v = v > 0.f ? v : 0.f;
                        op[col] = v + bf2f(xr[col]);
                    }
                } else {
                    const float* xr = x + (size_t)orow * DM;
#pragma unroll
                    for (int n = 0; n < 4; ++n) {
                        const int col = n0 + wc * 64 + n * 16 + lc;
                        float v = acc[m][n][reg] + bv[n];
                        v = v > 0.f ? v : 0.f;
                        op[col] = v + xr[col];
                    }
                }
            }
        }
    }
}

extern "C" void kernel_launch(void* const* d_in, const int* in_sizes, int n_in,
                              void* d_out, int out_size, void* d_ws, size_t ws_size,
                              hipStream_t stream) {
    const float* x    = (const float*)d_in[0];
    const float* sig  = (const float*)d_in[1];
    const float* W    = (const float*)d_in[2];
    const float* bias = (const float*)d_in[3];
    float* out = (float*)d_out;
    float* outIdx = out + (size_t)BATCH * DM;

    char* ws = (char*)d_ws;
    int* idx = (int*)ws;
    unsigned* ctrl = (unsigned*)(ws + CTRL_OFF);
    unsigned short* Qbf = (unsigned short*)(ws + QBF_OFF);
    int* perm = (int*)(ws + PERM_OFF);
    unsigned short* Xbf = (unsigned short*)(ws + XBF_OFF);
    unsigned short* Wb = (unsigned short*)(ws + WB_OFF);

    const bool full = ws_size >= WS_NEED;

    k_init<<<64, 256, 0, stream>>>(sig, ctrl, perm, Qbf);
    k_router<<<512, 256, 0, stream>>>(x, Qbf, ctrl, idx, outIdx, Xbf, full ? 1 : 0);
    k_scan<<<1, 64, 0, stream>>>(ctrl);
    k_perm<<<128, 256, 0, stream>>>(idx, ctrl, perm);
    if (full) {
        k_convw<<<8192, 256, 0, stream>>>(W, Wb);
        k_gemm<0><<<2176, 256, 0, stream>>>(Xbf, Wb, x, W, bias, perm, ctrl, out);
    } else {
        k_gemm<1><<<2176, 256, 0, stream>>>(Xbf, Wb, x, W, bias, perm, ctrl, out);
    }
}

// Round 6
// 251.367 us; speedup vs baseline: 4.2674x; 1.0071x over previous
//
#include <hip/hip_runtime.h>
#include <hip/hip_bf16.h>

#define BATCH   32768
#define DM      1024
#define NE      16
#define THRESHF 0.3f
#define MARGIN  0.02f

// ws layout (bytes)
// idx   @ 0          : int32[32768]            = 131072
// ctrl  @ 131072     : u32[2048] (8192 B)
//    [e*16]        counts (one 64B line per expert)
//    [256 + e*16]  cursor (strided)
//    [512..528]    tileBase int[17]
//    [1024..2047]  packT u32[1024] (pm | mm<<16 per dim)
// Qbf   @ 139264     : bf16[16*1024] ternary   = 32768
// perm  @ 172032     : int32[34816]            (prefilled 0 for pad slots)
// Xbf   @ 311296     : bf16[32768*1024]        = 67108864
// Wb    @ 67420160   : bf16[16*1024*1024]      = 33554432   (ends ~96.3 MB)
#define CTRL_OFF 131072
#define QBF_OFF  139264
#define PERM_OFF 172032
#define XBF_OFF  311296
#define WB_OFF   67420160ull
#define WS_NEED  (WB_OFF + (size_t)NE * DM * DM * 2)

typedef __attribute__((ext_vector_type(8))) short bf16x8;
typedef __attribute__((ext_vector_type(4))) float f32x4;

static __device__ __forceinline__ unsigned short f2bf(float f) {
    union { float f; unsigned u; } v; v.f = f;
    unsigned r = (v.u + 0x7FFFu + ((v.u >> 16) & 1u)) >> 16;  // RNE
    return (unsigned short)r;
}
static __device__ __forceinline__ float bf2f(unsigned short h) {
    union { unsigned u; float f; } v; v.u = ((unsigned)h) << 16;
    return v.f;
}

static __device__ __forceinline__ void gload_lds16(const void* g, void* s) {
    __builtin_amdgcn_global_load_lds(
        (const __attribute__((address_space(1))) void*)g,
        (__attribute__((address_space(3))) void*)s, 16, 0, 0);
}

// Zero ctrl, build ternary pack table + bf16 ternary Q, prefill perm with 0.
// 64 blocks x 256 -> t = 0..16383.
__global__ void k_init(const float* __restrict__ sig, unsigned* __restrict__ ctrl,
                       int* __restrict__ perm, unsigned short* __restrict__ Qbf) {
    const int t = blockIdx.x * 256 + threadIdx.x;
    if (t < 544) ctrl[t] = 0;
    if (t < 1024) {
        unsigned pm = 0, mm = 0;
#pragma unroll
        for (int e = 0; e < NE; ++e) {
            float s = sig[e * DM + t];
            pm |= (s > THRESHF ? 1u : 0u) << e;
            mm |= (s < -THRESHF ? 1u : 0u) << e;
        }
        ctrl[1024 + t] = pm | (mm << 16);
    }
    if (t < 8704) ((int4*)perm)[t] = make_int4(0, 0, 0, 0);
    {   // Qbf[e][d], t = e*1024+d
        float s = sig[t];
        Qbf[t] = s > THRESHF ? (unsigned short)0x3F80u
                             : (s < -THRESHF ? (unsigned short)0xBF80u : (unsigned short)0u);
    }
}

// MFMA router: scores = (x_hi @ Q^T) + (x_lo @ Q^T) in bf16 MFMA (f32 acc),
// top-2 margin; exact f64 fallback for close calls; writes Xbf (= x_hi).
__global__ __launch_bounds__(256) void k_router(const float* __restrict__ x,
                                                const unsigned short* __restrict__ Qbf,
                                                unsigned* __restrict__ ctrl,
                                                int* __restrict__ idx,
                                                float* __restrict__ outIdx,
                                                unsigned short* __restrict__ Xbf,
                                                int writeXbf) {
    const int t = threadIdx.x, w = t >> 6, l = t & 63;
    const int lc = l & 15, lr = l >> 4;
    const int wid = blockIdx.x * 4 + w;   // 0..2047
    const int row0 = wid * 16;
    const unsigned* packT = ctrl + 1024;

    const float* ax = x + (size_t)(row0 + lc) * DM + lr * 8;
    const unsigned short* qx = Qbf + (size_t)lc * DM + lr * 8;
    unsigned short* xb = Xbf + (size_t)(row0 + lc) * DM + lr * 8;

    f32x4 acc = (f32x4){0.f, 0.f, 0.f, 0.f};

    for (int kt = 0; kt < 16; ++kt) {
#pragma unroll
        for (int h = 0; h < 2; ++h) {
            const int ko = kt * 64 + h * 32;
            float4 v0 = *(const float4*)(ax + ko);
            float4 v1 = *(const float4*)(ax + ko + 4);
            bf16x8 q = *(const bf16x8*)(qx + ko);

            float f[8] = {v0.x, v0.y, v0.z, v0.w, v1.x, v1.y, v1.z, v1.w};
            bf16x8 ah, al;
#pragma unroll
            for (int j = 0; j < 8; ++j) {
                unsigned short hi = f2bf(f[j]);
                float r = f[j] - bf2f(hi);
                ah[j] = (short)hi;
                al[j] = (short)f2bf(r);
            }
            if (writeXbf) *(bf16x8*)(xb + ko) = ah;
            acc = __builtin_amdgcn_mfma_f32_16x16x32_bf16(ah, q, acc, 0, 0, 0);
            acc = __builtin_amdgcn_mfma_f32_16x16x32_bf16(al, q, acc, 0, 0, 0);
        }
    }
    // C layout: lane holds scores of expert e=lc for rows lr*4+reg.

    float bv[4]; int bi[4]; float gap[4];
#pragma unroll
    for (int reg = 0; reg < 4; ++reg) {
        float v = acc[reg]; int i = lc; float s = -3.4e38f;
#pragma unroll
        for (int m = 1; m < 16; m <<= 1) {
            float ov = __shfl_xor(v, m, 64);
            int oi = __shfl_xor(i, m, 64);
            float os = __shfl_xor(s, m, 64);
            bool take = (ov > v) || (ov == v && oi < i);
            float loser = take ? v : ov;
            v = take ? ov : v;
            i = take ? oi : i;
            s = fmaxf(fmaxf(s, os), loser);
        }
        bv[reg] = v; bi[reg] = i; gap[reg] = v - s;
    }

    unsigned flagsw = 0;
#pragma unroll
    for (int reg = 0; reg < 4; ++reg)
        flagsw |= (gap[reg] < MARGIN ? 1u : 0u) << reg;

    if (__any(lc == 0 && flagsw != 0)) {   // rare exact path
#pragma unroll
        for (int reg = 0; reg < 4; ++reg) {
            for (int g = 0; g < 4; ++g) {
                const unsigned fw = __shfl(flagsw, g * 16, 64);
                if ((fw >> reg) & 1u) {
                    const int row = row0 + g * 4 + reg;
                    const float* xr = x + (size_t)row * DM;
                    float xv[16]; unsigned mk[16];
#pragma unroll
                    for (int k2 = 0; k2 < 16; ++k2) {
                        xv[k2] = xr[k2 * 64 + l];
                        mk[k2] = packT[k2 * 64 + l];
                    }
                    double best = 0.0; int bbi = 0;
                    for (int e = 0; e < 16; ++e) {
                        double a = 0.0;
#pragma unroll
                        for (int k2 = 0; k2 < 16; ++k2) {
                            const int pb = (int)((mk[k2] >> e) & 1u);
                            const int mb = (int)((mk[k2] >> (16 + e)) & 1u);
                            a += pb ? (double)xv[k2] : (mb ? -(double)xv[k2] : 0.0);
                        }
#pragma unroll
                        for (int m = 1; m < 64; m <<= 1) a += __shfl_xor(a, m, 64);
                        if (e == 0 || a > best) { best = a; bbi = e; }
                    }
                    if (lr == g && lc == 0) bi[reg] = bbi;
                }
            }
        }
    }

    if (lc == 0) {
#pragma unroll
        for (int reg = 0; reg < 4; ++reg) {
            const int row = row0 + lr * 4 + reg;
            idx[row] = bi[reg];
            outIdx[row] = (float)bi[reg];
            atomicAdd(&ctrl[bi[reg] * 16], 1u);
        }
    }
}

// Tile-granular prefix: tileBase[e] = #128-row tiles before expert e.
__global__ void k_scan(unsigned* __restrict__ ctrl) {
    if (threadIdx.x == 0) {
        int* tileBase = (int*)(ctrl + 512);
        int acc = 0;
        for (int e = 0; e < NE; ++e) {
            tileBase[e] = acc;
            acc += (int)((ctrl[e * 16] + 127u) / 128u);
        }
        tileBase[NE] = acc;
    }
}

// Perm build: block-aggregated ranks (LDS hist -> 16 global atomics/block).
__global__ __launch_bounds__(256) void k_perm(const int* __restrict__ idx,
                                              unsigned* __restrict__ ctrl,
                                              int* __restrict__ perm) {
    __shared__ unsigned hcnt[16];
    __shared__ unsigned hbase[16];
    const int t = threadIdx.x;
    const int row = blockIdx.x * 256 + t;
    const int* tileBase = (const int*)(ctrl + 512);
    if (t < 16) hcnt[t] = 0;
    __syncthreads();
    const int e = idx[row];
    const unsigned lrank = atomicAdd(&hcnt[e], 1u);
    __syncthreads();
    if (t < 16) hbase[t] = atomicAdd(&ctrl[256 + t * 16], hcnt[t]);
    __syncthreads();
    perm[tileBase[e] * 128 + hbase[e] + lrank] = row;
}

// W f32 -> bf16 (16M elems, 8 per thread).
__global__ __launch_bounds__(256) void k_convw(const float* __restrict__ W,
                                               unsigned short* __restrict__ Wb) {
    const size_t g = ((size_t)blockIdx.x * 256 + threadIdx.x) * 8;
    float4 a = *(const float4*)&W[g];
    float4 b = *(const float4*)&W[g + 4];
    *(ushort4*)&Wb[g]     = make_ushort4(f2bf(a.x), f2bf(a.y), f2bf(a.z), f2bf(a.w));
    *(ushort4*)&Wb[g + 4] = make_ushort4(f2bf(b.x), f2bf(b.y), f2bf(b.z), f2bf(b.w));
}

// Grouped bf16 GEMM: 128x128 tile, BK=32, 4 waves (2x2), 16x16x32 MFMA.
// LDS chunk-swizzle (both-sides, rule #21): slot (row r, s) holds data-chunk
// (s - (r>>1))&3. Stage: lane c sources chunk hsw = ((c&3)-((c>>3)&3))&3.
// Read: data-chunk lr of row r lives at slot s = (lr + (r>>1))&3.
// Bank math: slot8 = (r&1)*4 + s covers all 8 16B-slots 2x per 16 lanes ->
// conflict-free (2 lanes/bank is free, m136).
// MODE 0: double-buffered LDS, stage-ahead, one barrier per K-step;
//         A gathered from Xbf via perm; B from Wb; XCD-local (bx,ny) decode.
// MODE 1 (small ws): reg-staged f32->bf16 conversion from x and W.
// Epilogue: +bias, ReLU, +bf16 residual from Xbf, scatter-store to out rows.
template <int MODE>
__global__ __launch_bounds__(256) void k_gemm(const unsigned short* __restrict__ Xbf,
                                              const unsigned short* __restrict__ Wb,
                                              const float* __restrict__ x,
                                              const float* __restrict__ W,
                                              const float* __restrict__ bias,
                                              const int* __restrict__ perm,
                                              const unsigned* __restrict__ ctrl,
                                              float* __restrict__ out) {
    __shared__ unsigned short A_lds[2][128 * 32];
    __shared__ unsigned short B_lds[2][128 * 32];

    const int* tileBase = (const int*)(ctrl + 512);

    // flat = 0..2175: xcd = flat&7; all 8 ny-siblings of one bx share an XCD.
    int bx, ny;
    {
        const int flat = blockIdx.x;
        const int xcd = flat & 7, s2 = flat >> 3;
        bx = xcd * 34 + (s2 >> 3);
        ny = s2 & 7;
    }
    const int total = tileBase[NE];
    if (bx >= total) return;
    int e = 0;
    while (e < NE - 1 && tileBase[e + 1] <= bx) ++e;
    const int ltile = bx - tileBase[e];
    const int valid = (int)ctrl[e * 16] - ltile * 128;  // 1..128 valid rows
    const int n0 = ny * 128;

    const int t = threadIdx.x, w = t >> 6, l = t & 63;
    const int wr = w >> 1, wc = w & 1;
    const int lc = l & 15, lr = l >> 4;
    const int hsw = ((t & 3) - ((t >> 3) & 3)) & 3;     // staged data-chunk
    const int ssw = (lr + (lc >> 1)) & 3;               // read slot-chunk

    f32x4 acc[4][4];
#pragma unroll
    for (int m = 0; m < 4; ++m)
#pragma unroll
        for (int n = 0; n < 4; ++n) acc[m][n] = (f32x4){0.f, 0.f, 0.f, 0.f};

    const size_t aRowBase = (size_t)bx * 128;
    const unsigned short* Bg = Wb + ((size_t)e * DM + n0) * DM;

    if (MODE == 0) {
        // Per-lane gathered A sources (perm prefilled 0 for pad slots).
        const int r0 = t >> 2;
        const int prow0 = perm[aRowBase + r0];
        const int prow1 = perm[aRowBase + 64 + r0];
        const unsigned short* a0 = Xbf + (size_t)prow0 * DM + hsw * 8;
        const unsigned short* a1 = Xbf + (size_t)prow1 * DM + hsw * 8;

        // prologue: stage tile 0 into buf 0
        gload_lds16(a0, &A_lds[0][(size_t)(w * 64) * 8]);
        gload_lds16(a1, &A_lds[0][(size_t)(256 + w * 64) * 8]);
#pragma unroll
        for (int rd = 0; rd < 2; ++rd) {
            const int c = rd * 256 + t;
            gload_lds16(Bg + (size_t)(c >> 2) * DM + hsw * 8,
                        &B_lds[0][(size_t)(rd * 256 + w * 64) * 8]);
        }
        __syncthreads();

        int cur = 0;
        for (int kt = 0; kt < DM / 32; ++kt) {
            if (kt < DM / 32 - 1) {  // stage-ahead: next tile into buf^1
                const int ko = (kt + 1) * 32;
                gload_lds16(a0 + ko, &A_lds[cur ^ 1][(size_t)(w * 64) * 8]);
                gload_lds16(a1 + ko, &A_lds[cur ^ 1][(size_t)(256 + w * 64) * 8]);
#pragma unroll
                for (int rd = 0; rd < 2; ++rd) {
                    const int c = rd * 256 + t;
                    gload_lds16(Bg + (size_t)(c >> 2) * DM + ko + hsw * 8,
                                &B_lds[cur ^ 1][(size_t)(rd * 256 + w * 64) * 8]);
                }
            }

            bf16x8 af[4], bf[4];
#pragma unroll
            for (int m = 0; m < 4; ++m)
                af[m] = *(const bf16x8*)&A_lds[cur][(wr * 64 + m * 16 + lc) * 32 + ssw * 8];
#pragma unroll
            for (int n = 0; n < 4; ++n)
                bf[n] = *(const bf16x8*)&B_lds[cur][(wc * 64 + n * 16 + lc) * 32 + ssw * 8];
#pragma unroll
            for (int m = 0; m < 4; ++m)
#pragma unroll
                for (int n = 0; n < 4; ++n)
                    acc[m][n] = __builtin_amdgcn_mfma_f32_16x16x32_bf16(af[m], bf[n], acc[m][n], 0, 0, 0);

            if (kt < DM / 32 - 1) __syncthreads();  // vmcnt(0)+barrier: buf^1 ready
            cur ^= 1;
        }
    } else {
        for (int kt = 0; kt < DM / 32; ++kt) {
            __syncthreads();
#pragma unroll
            for (int rd = 0; rd < 2; ++rd) {
                const int c = rd * 256 + t;
                const int r = c >> 2;
                const float* wp = W + ((size_t)e * DM + n0 + r) * DM + kt * 32 + hsw * 8;
                float4 b0 = *(const float4*)wp;
                float4 b1 = *(const float4*)(wp + 4);
                *(ushort4*)&B_lds[0][c * 8]     = make_ushort4(f2bf(b0.x), f2bf(b0.y), f2bf(b0.z), f2bf(b0.w));
                *(ushort4*)&B_lds[0][c * 8 + 4] = make_ushort4(f2bf(b1.x), f2bf(b1.y), f2bf(b1.z), f2bf(b1.w));
                ushort4 p0 = make_ushort4(0, 0, 0, 0), p1 = p0;
                if (r < valid) {
                    const int orow = perm[aRowBase + r];
                    const float* xp = x + (size_t)orow * DM + kt * 32 + hsw * 8;
                    float4 q0 = *(const float4*)xp;
                    float4 q1 = *(const float4*)(xp + 4);
                    p0 = make_ushort4(f2bf(q0.x), f2bf(q0.y), f2bf(q0.z), f2bf(q0.w));
                    p1 = make_ushort4(f2bf(q1.x), f2bf(q1.y), f2bf(q1.z), f2bf(q1.w));
                }
                *(ushort4*)&A_lds[0][c * 8]     = p0;
                *(ushort4*)&A_lds[0][c * 8 + 4] = p1;
            }
            __syncthreads();

            bf16x8 af[4], bf[4];
#pragma unroll
            for (int m = 0; m < 4; ++m)
                af[m] = *(const bf16x8*)&A_lds[0][(wr * 64 + m * 16 + lc) * 32 + ssw * 8];
#pragma unroll
            for (int n = 0; n < 4; ++n)
                bf[n] = *(const bf16x8*)&B_lds[0][(wc * 64 + n * 16 + lc) * 32 + ssw * 8];
#pragma unroll
            for (int m = 0; m < 4; ++m)
#pragma unroll
                for (int n = 0; n < 4; ++n)
                    acc[m][n] = __builtin_amdgcn_mfma_f32_16x16x32_bf16(af[m], bf[n], acc[m][n], 0, 0, 0);
        }
    }

    float bv[4];
#pragma unroll
    for (int n = 0; n < 4; ++n) bv[n] = bias[e * DM + n0 + wc * 64 + n * 16 + lc];

#pragma unroll
    for (int m = 0; m < 4; ++m) {
#pragma unroll
        for (int reg = 0; reg < 4; ++reg) {
            const int rit = wr * 64 + m * 16 + lr * 4 + reg;  // row in tile
            if (rit < valid) {
                const int orow = perm[aRowBase + rit];
                float* op = out + (size_t)orow * DM;
                if (MODE == 0) {
                    const unsigned short* xr = Xbf + (size_t)orow * DM;
#pragma unroll
                    for (int n = 0; n < 4; ++n) {
                        const int col = n0 + wc * 64 + n * 16 + lc;
                        float v = acc[m][n][reg] + bv[n];
                        v = v > 0.f ? v : 0.f;
                        op[col] = v + bf2f(xr[col]);
                    }
                } else {
                    const float* xr = x + (size_t)orow * DM;
#pragma unroll
                    for (int n = 0; n < 4; ++n) {
                        const int col = n0 + wc * 64 + n * 16 + lc;
                        float v = acc[m][n][reg] + bv[n];
                        v = v > 0.f ? v : 0.f;
                        op[col] = v + xr[col];
                    }
                }
            }
        }
    }
}

extern "C" void kernel_launch(void* const* d_in, const int* in_sizes, int n_in,
                              void* d_out, int out_size, void* d_ws, size_t ws_size,
                              hipStream_t stream) {
    const float* x    = (const float*)d_in[0];
    const float* sig  = (const float*)d_in[1];
    const float* W    = (const float*)d_in[2];
    const float* bias = (const float*)d_in[3];
    float* out = (float*)d_out;
    float* outIdx = out + (size_t)BATCH * DM;

    char* ws = (char*)d_ws;
    int* idx = (int*)ws;
    unsigned* ctrl = (unsigned*)(ws + CTRL_OFF);
    unsigned short* Qbf = (unsigned short*)(ws + QBF_OFF);
    int* perm = (int*)(ws + PERM_OFF);
    unsigned short* Xbf = (unsigned short*)(ws + XBF_OFF);
    unsigned short* Wb = (unsigned short*)(ws + WB_OFF);

    const bool full = ws_size >= WS_NEED;

    k_init<<<64, 256, 0, stream>>>(sig, ctrl, perm, Qbf);
    k_router<<<512, 256, 0, stream>>>(x, Qbf, ctrl, idx, outIdx, Xbf, full ? 1 : 0);
    k_scan<<<1, 64, 0, stream>>>(ctrl);
    k_perm<<<128, 256, 0, stream>>>(idx, ctrl, perm);
    if (full) {
        k_convw<<<8192, 256, 0, stream>>>(W, Wb);
        k_gemm<0><<<2176, 256, 0, stream>>>(Xbf, Wb, x, W, bias, perm, ctrl, out);
    } else {
        k_gemm<1><<<2176, 256, 0, stream>>>(Xbf, Wb, x, W, bias, perm, ctrl, out);
    }
}

// Round 7
// 247.750 us; speedup vs baseline: 4.3296x; 1.0146x over previous
//
#include <hip/hip_runtime.h>
#include <hip/hip_bf16.h>

#define BATCH   32768
#define DM      1024
#define NE      16
#define THRESHF 0.3f
#define MARGIN  0.02f

// ws layout (bytes)
// idx   @ 0          : int32[32768]            = 131072
// ctrl  @ 131072     : u32[2048] (8192 B)
//    [e*16]        counts (one 64B line per expert)
//    [256 + e*16]  cursor (strided)
//    [512..528]    tileBase int[17]
//    [1024..2047]  packT u32[1024] (pm | mm<<16 per dim)
// Qbf   @ 139264     : bf16[16*1024] ternary   = 32768
// perm  @ 172032     : int32[34816]            (prefilled 0 for pad slots)
// Xbf   @ 311296     : bf16[32768*1024]        = 67108864
// Wb    @ 67420160   : bf16[16*1024*1024]      = 33554432   (ends ~96.3 MB)
#define CTRL_OFF 131072
#define QBF_OFF  139264
#define PERM_OFF 172032
#define XBF_OFF  311296
#define WB_OFF   67420160ull
#define WS_NEED  (WB_OFF + (size_t)NE * DM * DM * 2)

typedef __attribute__((ext_vector_type(8))) short bf16x8;
typedef __attribute__((ext_vector_type(4))) float f32x4;

static __device__ __forceinline__ unsigned short f2bf(float f) {
    union { float f; unsigned u; } v; v.f = f;
    unsigned r = (v.u + 0x7FFFu + ((v.u >> 16) & 1u)) >> 16;  // RNE
    return (unsigned short)r;
}
static __device__ __forceinline__ float bf2f(unsigned short h) {
    union { unsigned u; float f; } v; v.u = ((unsigned)h) << 16;
    return v.f;
}

static __device__ __forceinline__ void gload_lds16(const void* g, void* s) {
    __builtin_amdgcn_global_load_lds(
        (const __attribute__((address_space(1))) void*)g,
        (__attribute__((address_space(3))) void*)s, 16, 0, 0);
}

// Zero ctrl, build ternary pack table + bf16 ternary Q, prefill perm with 0.
// 64 blocks x 256 -> t = 0..16383.
__global__ void k_init(const float* __restrict__ sig, unsigned* __restrict__ ctrl,
                       int* __restrict__ perm, unsigned short* __restrict__ Qbf) {
    const int t = blockIdx.x * 256 + threadIdx.x;
    if (t < 544) ctrl[t] = 0;
    if (t < 1024) {
        unsigned pm = 0, mm = 0;
#pragma unroll
        for (int e = 0; e < NE; ++e) {
            float s = sig[e * DM + t];
            pm |= (s > THRESHF ? 1u : 0u) << e;
            mm |= (s < -THRESHF ? 1u : 0u) << e;
        }
        ctrl[1024 + t] = pm | (mm << 16);
    }
    if (t < 8704) ((int4*)perm)[t] = make_int4(0, 0, 0, 0);
    {   // Qbf[e][d], t = e*1024+d
        float s = sig[t];
        Qbf[t] = s > THRESHF ? (unsigned short)0x3F80u
                             : (s < -THRESHF ? (unsigned short)0xBF80u : (unsigned short)0u);
    }
}

// MFMA router: scores = (x_hi @ Q^T) + (x_lo @ Q^T) in bf16 MFMA (f32 acc),
// top-2 margin; exact f64 fallback for close calls; writes Xbf (= x_hi).
__global__ __launch_bounds__(256) void k_router(const float* __restrict__ x,
                                                const unsigned short* __restrict__ Qbf,
                                                unsigned* __restrict__ ctrl,
                                                int* __restrict__ idx,
                                                float* __restrict__ outIdx,
                                                unsigned short* __restrict__ Xbf,
                                                int writeXbf) {
    const int t = threadIdx.x, w = t >> 6, l = t & 63;
    const int lc = l & 15, lr = l >> 4;
    const int wid = blockIdx.x * 4 + w;   // 0..2047
    const int row0 = wid * 16;
    const unsigned* packT = ctrl + 1024;

    const float* ax = x + (size_t)(row0 + lc) * DM + lr * 8;
    const unsigned short* qx = Qbf + (size_t)lc * DM + lr * 8;
    unsigned short* xb = Xbf + (size_t)(row0 + lc) * DM + lr * 8;

    f32x4 acc = (f32x4){0.f, 0.f, 0.f, 0.f};

    for (int kt = 0; kt < 16; ++kt) {
#pragma unroll
        for (int h = 0; h < 2; ++h) {
            const int ko = kt * 64 + h * 32;
            float4 v0 = *(const float4*)(ax + ko);
            float4 v1 = *(const float4*)(ax + ko + 4);
            bf16x8 q = *(const bf16x8*)(qx + ko);

            float f[8] = {v0.x, v0.y, v0.z, v0.w, v1.x, v1.y, v1.z, v1.w};
            bf16x8 ah, al;
#pragma unroll
            for (int j = 0; j < 8; ++j) {
                unsigned short hi = f2bf(f[j]);
                float r = f[j] - bf2f(hi);
                ah[j] = (short)hi;
                al[j] = (short)f2bf(r);
            }
            if (writeXbf) *(bf16x8*)(xb + ko) = ah;
            acc = __builtin_amdgcn_mfma_f32_16x16x32_bf16(ah, q, acc, 0, 0, 0);
            acc = __builtin_amdgcn_mfma_f32_16x16x32_bf16(al, q, acc, 0, 0, 0);
        }
    }
    // C layout: lane holds scores of expert e=lc for rows lr*4+reg.

    float bv[4]; int bi[4]; float gap[4];
#pragma unroll
    for (int reg = 0; reg < 4; ++reg) {
        float v = acc[reg]; int i = lc; float s = -3.4e38f;
#pragma unroll
        for (int m = 1; m < 16; m <<= 1) {
            float ov = __shfl_xor(v, m, 64);
            int oi = __shfl_xor(i, m, 64);
            float os = __shfl_xor(s, m, 64);
            bool take = (ov > v) || (ov == v && oi < i);
            float loser = take ? v : ov;
            v = take ? ov : v;
            i = take ? oi : i;
            s = fmaxf(fmaxf(s, os), loser);
        }
        bv[reg] = v; bi[reg] = i; gap[reg] = v - s;
    }

    unsigned flagsw = 0;
#pragma unroll
    for (int reg = 0; reg < 4; ++reg)
        flagsw |= (gap[reg] < MARGIN ? 1u : 0u) << reg;

    if (__any(lc == 0 && flagsw != 0)) {   // rare exact path
#pragma unroll
        for (int reg = 0; reg < 4; ++reg) {
            for (int g = 0; g < 4; ++g) {
                const unsigned fw = __shfl(flagsw, g * 16, 64);
                if ((fw >> reg) & 1u) {
                    const int row = row0 + g * 4 + reg;
                    const float* xr = x + (size_t)row * DM;
                    float xv[16]; unsigned mk[16];
#pragma unroll
                    for (int k2 = 0; k2 < 16; ++k2) {
                        xv[k2] = xr[k2 * 64 + l];
                        mk[k2] = packT[k2 * 64 + l];
                    }
                    double best = 0.0; int bbi = 0;
                    for (int e = 0; e < 16; ++e) {
                        double a = 0.0;
#pragma unroll
                        for (int k2 = 0; k2 < 16; ++k2) {
                            const int pb = (int)((mk[k2] >> e) & 1u);
                            const int mb = (int)((mk[k2] >> (16 + e)) & 1u);
                            a += pb ? (double)xv[k2] : (mb ? -(double)xv[k2] : 0.0);
                        }
#pragma unroll
                        for (int m = 1; m < 64; m <<= 1) a += __shfl_xor(a, m, 64);
                        if (e == 0 || a > best) { best = a; bbi = e; }
                    }
                    if (lr == g && lc == 0) bi[reg] = bbi;
                }
            }
        }
    }

    if (lc == 0) {
#pragma unroll
        for (int reg = 0; reg < 4; ++reg) {
            const int row = row0 + lr * 4 + reg;
            idx[row] = bi[reg];
            outIdx[row] = (float)bi[reg];
            atomicAdd(&ctrl[bi[reg] * 16], 1u);
        }
    }
}

// Tile-granular prefix: tileBase[e] = #128-row tiles before expert e.
__global__ void k_scan(unsigned* __restrict__ ctrl) {
    if (threadIdx.x == 0) {
        int* tileBase = (int*)(ctrl + 512);
        int acc = 0;
        for (int e = 0; e < NE; ++e) {
            tileBase[e] = acc;
            acc += (int)((ctrl[e * 16] + 127u) / 128u);
        }
        tileBase[NE] = acc;
    }
}

// Perm build: block-aggregated ranks (LDS hist -> 16 global atomics/block).
__global__ __launch_bounds__(256) void k_perm(const int* __restrict__ idx,
                                              unsigned* __restrict__ ctrl,
                                              int* __restrict__ perm) {
    __shared__ unsigned hcnt[16];
    __shared__ unsigned hbase[16];
    const int t = threadIdx.x;
    const int row = blockIdx.x * 256 + t;
    const int* tileBase = (const int*)(ctrl + 512);
    if (t < 16) hcnt[t] = 0;
    __syncthreads();
    const int e = idx[row];
    const unsigned lrank = atomicAdd(&hcnt[e], 1u);
    __syncthreads();
    if (t < 16) hbase[t] = atomicAdd(&ctrl[256 + t * 16], hcnt[t]);
    __syncthreads();
    perm[tileBase[e] * 128 + hbase[e] + lrank] = row;
}

// W f32 -> bf16 (16M elems, 8 per thread).
__global__ __launch_bounds__(256) void k_convw(const float* __restrict__ W,
                                               unsigned short* __restrict__ Wb) {
    const size_t g = ((size_t)blockIdx.x * 256 + threadIdx.x) * 8;
    float4 a = *(const float4*)&W[g];
    float4 b = *(const float4*)&W[g + 4];
    *(ushort4*)&Wb[g]     = make_ushort4(f2bf(a.x), f2bf(a.y), f2bf(a.z), f2bf(a.w));
    *(ushort4*)&Wb[g + 4] = make_ushort4(f2bf(b.x), f2bf(b.y), f2bf(b.z), f2bf(b.w));
}

// Grouped bf16 GEMM: 128x128 tile, BK=32, 4 waves (2x2), 16x16x32 MFMA.
// LDS chunk-swizzle (both-sides, rule #21) as in R6 — conflict-free.
// MODE 0: 3-buffer pipeline with counted vmcnt (T4): raw s_barrier, loads
//   stay in flight across barriers. Per iter (cur = t%3):
//     s_waitcnt vmcnt(4)   // stage(t) landed; stage(t+1) still in flight
//     s_barrier            // all waves: stage(t) visible, prev reads done
//     STAGE(t+2 -> buf[(t+2)%3])   // safe: its readers finished iter t-1
//     ds_read buf[cur]; MFMA (compiler inserts lgkm waits)
//   Race audit: stage(t+2) writes buf[(t-1)%3]; every wave's iter-(t-1)
//   ds_reads complete (lgkm dep before its MFMAs) before it reaches the
//   iter-t barrier, and the stage is issued after that barrier.
// MODE 1 (small ws): reg-staged f32->bf16 conversion (2-phase, unchanged).
// Epilogue: +bias, ReLU, +bf16 residual from Xbf, scatter-store to out rows.
template <int MODE>
__global__ __launch_bounds__(256) void k_gemm(const unsigned short* __restrict__ Xbf,
                                              const unsigned short* __restrict__ Wb,
                                              const float* __restrict__ x,
                                              const float* __restrict__ W,
                                              const float* __restrict__ bias,
                                              const int* __restrict__ perm,
                                              const unsigned* __restrict__ ctrl,
                                              float* __restrict__ out) {
    __shared__ unsigned short A_lds[3][128 * 32];
    __shared__ unsigned short B_lds[3][128 * 32];

    const int* tileBase = (const int*)(ctrl + 512);

    // flat = 0..2175: xcd = flat&7; all 8 ny-siblings of one bx share an XCD.
    int bx, ny;
    {
        const int flat = blockIdx.x;
        const int xcd = flat & 7, s2 = flat >> 3;
        bx = xcd * 34 + (s2 >> 3);
        ny = s2 & 7;
    }
    const int total = tileBase[NE];
    if (bx >= total) return;
    int e = 0;
    while (e < NE - 1 && tileBase[e + 1] <= bx) ++e;
    const int ltile = bx - tileBase[e];
    const int valid = (int)ctrl[e * 16] - ltile * 128;  // 1..128 valid rows
    const int n0 = ny * 128;

    const int t = threadIdx.x, w = t >> 6, l = t & 63;
    const int wr = w >> 1, wc = w & 1;
    const int lc = l & 15, lr = l >> 4;
    const int hsw = ((t & 3) - ((t >> 3) & 3)) & 3;     // staged data-chunk
    const int ssw = (lr + (lc >> 1)) & 3;               // read slot-chunk

    f32x4 acc[4][4];
#pragma unroll
    for (int m = 0; m < 4; ++m)
#pragma unroll
        for (int n = 0; n < 4; ++n) acc[m][n] = (f32x4){0.f, 0.f, 0.f, 0.f};

    const size_t aRowBase = (size_t)bx * 128;
    const unsigned short* Bg = Wb + ((size_t)e * DM + n0) * DM;

    if (MODE == 0) {
        // Per-lane gathered A sources (perm prefilled 0 for pad slots).
        const int r0 = t >> 2;
        const int prow0 = perm[aRowBase + r0];
        const int prow1 = perm[aRowBase + 64 + r0];
        const unsigned short* a0 = Xbf + (size_t)prow0 * DM + hsw * 8;
        const unsigned short* a1 = Xbf + (size_t)prow1 * DM + hsw * 8;
        const unsigned short* b0 = Bg + (size_t)(t >> 2) * DM + hsw * 8;
        const unsigned short* b1 = Bg + (size_t)(64 + (t >> 2)) * DM + hsw * 8;

        auto STAGE = [&](int kt, int buf) {   // 4 VMEM ops/thread
            const int ko = kt * 32;
            gload_lds16(a0 + ko, &A_lds[buf][(size_t)(w * 64) * 8]);
            gload_lds16(a1 + ko, &A_lds[buf][(size_t)(256 + w * 64) * 8]);
            gload_lds16(b0 + ko, &B_lds[buf][(size_t)(w * 64) * 8]);
            gload_lds16(b1 + ko, &B_lds[buf][(size_t)(256 + w * 64) * 8]);
        };

        STAGE(0, 0);
        STAGE(1, 1);

        const int NT = DM / 32;  // 32
        int cur = 0;
        for (int kt = 0; kt < NT; ++kt) {
            if (kt + 1 < NT) asm volatile("s_waitcnt vmcnt(4)" ::: "memory");
            else             asm volatile("s_waitcnt vmcnt(0)" ::: "memory");
            __builtin_amdgcn_sched_barrier(0);
            __builtin_amdgcn_s_barrier();
            __builtin_amdgcn_sched_barrier(0);

            if (kt + 2 < NT) {
                const int nb = (cur + 2 >= 3) ? cur - 1 : cur + 2;
                STAGE(kt + 2, nb);
            }

            bf16x8 af[4], bf[4];
#pragma unroll
            for (int m = 0; m < 4; ++m)
                af[m] = *(const bf16x8*)&A_lds[cur][(wr * 64 + m * 16 + lc) * 32 + ssw * 8];
#pragma unroll
            for (int n = 0; n < 4; ++n)
                bf[n] = *(const bf16x8*)&B_lds[cur][(wc * 64 + n * 16 + lc) * 32 + ssw * 8];
#pragma unroll
            for (int m = 0; m < 4; ++m)
#pragma unroll
                for (int n = 0; n < 4; ++n)
                    acc[m][n] = __builtin_amdgcn_mfma_f32_16x16x32_bf16(af[m], bf[n], acc[m][n], 0, 0, 0);

            cur = (cur + 1 >= 3) ? 0 : cur + 1;
        }
    } else {
        for (int kt = 0; kt < DM / 32; ++kt) {
            __syncthreads();
#pragma unroll
            for (int rd = 0; rd < 2; ++rd) {
                const int c = rd * 256 + t;
                const int r = c >> 2;
                const float* wp = W + ((size_t)e * DM + n0 + r) * DM + kt * 32 + hsw * 8;
                float4 q0 = *(const float4*)wp;
                float4 q1 = *(const float4*)(wp + 4);
                *(ushort4*)&B_lds[0][c * 8]     = make_ushort4(f2bf(q0.x), f2bf(q0.y), f2bf(q0.z), f2bf(q0.w));
                *(ushort4*)&B_lds[0][c * 8 + 4] = make_ushort4(f2bf(q1.x), f2bf(q1.y), f2bf(q1.z), f2bf(q1.w));
                ushort4 p0 = make_ushort4(0, 0, 0, 0), p1 = p0;
                if (r < valid) {
                    const int orow = perm[aRowBase + r];
                    const float* xp = x + (size_t)orow * DM + kt * 32 + hsw * 8;
                    float4 u0 = *(const float4*)xp;
                    float4 u1 = *(const float4*)(xp + 4);
                    p0 = make_ushort4(f2bf(u0.x), f2bf(u0.y), f2bf(u0.z), f2bf(u0.w));
                    p1 = make_ushort4(f2bf(u1.x), f2bf(u1.y), f2bf(u1.z), f2bf(u1.w));
                }
                *(ushort4*)&A_lds[0][c * 8]     = p0;
                *(ushort4*)&A_lds[0][c * 8 + 4] = p1;
            }
            __syncthreads();

            bf16x8 af[4], bf[4];
#pragma unroll
            for (int m = 0; m < 4; ++m)
                af[m] = *(const bf16x8*)&A_lds[0][(wr * 64 + m * 16 + lc) * 32 + ssw * 8];
#pragma unroll
            for (int n = 0; n < 4; ++n)
                bf[n] = *(const bf16x8*)&B_lds[0][(wc * 64 + n * 16 + lc) * 32 + ssw * 8];
#pragma unroll
            for (int m = 0; m < 4; ++m)
#pragma unroll
                for (int n = 0; n < 4; ++n)
                    acc[m][n] = __builtin_amdgcn_mfma_f32_16x16x32_bf16(af[m], bf[n], acc[m][n], 0, 0, 0);
        }
    }

    float bvv[4];
#pragma unroll
    for (int n = 0; n < 4; ++n) bvv[n] = bias[e * DM + n0 + wc * 64 + n * 16 + lc];

#pragma unroll
    for (int m = 0; m < 4; ++m) {
#pragma unroll
        for (int reg = 0; reg < 4; ++reg) {
            const int rit = wr * 64 + m * 16 + lr * 4 + reg;  // row in tile
            if (rit < valid) {
                const int orow = perm[aRowBase + rit];
                float* op = out + (size_t)orow * DM;
                if (MODE == 0) {
                    const unsigned short* xr = Xbf + (size_t)orow * DM;
#pragma unroll
                    for (int n = 0; n < 4; ++n) {
                        const int col = n0 + wc * 64 + n * 16 + lc;
                        float v = acc[m][n][reg] + bvv[n];
                        v = v > 0.f ? v : 0.f;
                        op[col] = v + bf2f(xr[col]);
                    }
                } else {
                    const float* xr = x + (size_t)orow * DM;
#pragma unroll
                    for (int n = 0; n < 4; ++n) {
                        const int col = n0 + wc * 64 + n * 16 + lc;
                        float v = acc[m][n][reg] + bvv[n];
                        v = v > 0.f ? v : 0.f;
                        op[col] = v + xr[col];
                    }
                }
            }
        }
    }
}

extern "C" void kernel_launch(void* const* d_in, const int* in_sizes, int n_in,
                              void* d_out, int out_size, void* d_ws, size_t ws_size,
                              hipStream_t stream) {
    const float* x    = (const float*)d_in[0];
    const float* sig  = (const float*)d_in[1];
    const float* W    = (const float*)d_in[2];
    const float* bias = (const float*)d_in[3];
    float* out = (float*)d_out;
    float* outIdx = out + (size_t)BATCH * DM;

    char* ws = (char*)d_ws;
    int* idx = (int*)ws;
    unsigned* ctrl = (unsigned*)(ws + CTRL_OFF);
    unsigned short* Qbf = (unsigned short*)(ws + QBF_OFF);
    int* perm = (int*)(ws + PERM_OFF);
    unsigned short* Xbf = (unsigned short*)(ws + XBF_OFF);
    unsigned short* Wb = (unsigned short*)(ws + WB_OFF);

    const bool full = ws_size >= WS_NEED;

    k_init<<<64, 256, 0, stream>>>(sig, ctrl, perm, Qbf);
    k_router<<<512, 256, 0, stream>>>(x, Qbf, ctrl, idx, outIdx, Xbf, full ? 1 : 0);
    k_scan<<<1, 64, 0, stream>>>(ctrl);
    k_perm<<<128, 256, 0, stream>>>(idx, ctrl, perm);
    if (full) {
        k_convw<<<8192, 256, 0, stream>>>(W, Wb);
        k_gemm<0><<<2176, 256, 0, stream>>>(Xbf, Wb, x, W, bias, perm, ctrl, out);
    } else {
        k_gemm<1><<<2176, 256, 0, stream>>>(Xbf, Wb, x, W, bias, perm, ctrl, out);
    }
}